// Round 6
// baseline (341.696 us; speedup 1.0000x reference)
//
#include <hip/hip_runtime.h>
#include <stdint.h>

#define DIMC 1536
#define LTOK 3072
#define HEADS 12
#define HD 128
#define FS 384            // H*W = 16*24
#define MAXATTN 1920
#define HTOK 1152         // first token with qf>=3 (2-chunk rows)
#define NHT 1920          // number of heavy tokens

typedef __attribute__((ext_vector_type(4))) float f32x4;
typedef __attribute__((ext_vector_type(8))) short bf16x8;

__device__ __forceinline__ unsigned short f2bf(float f) {
  union { float f; unsigned int u; } c; c.f = f;
  unsigned int u = c.u + 0x7fffu + ((c.u >> 16) & 1u);   // RNE
  return (unsigned short)(u >> 16);
}
__device__ __forceinline__ float bf2f(unsigned short s) {
  union { unsigned int u; float f; } c; c.u = (unsigned int)s << 16; return c.f;
}

// async global->LDS DMA, 16B per lane; LDS dest must be wave-uniform base +
// lane*16 (our staging offsets are tid*16B -> satisfied).
__device__ __forceinline__ void dma16(const void* g, void* l) {
  __builtin_amdgcn_global_load_lds(
      (const __attribute__((address_space(1))) unsigned int*)g,
      (__attribute__((address_space(3))) unsigned int*)l, 16, 0, 0);
}

// ---------------- fused fp32 -> bf16 conversion for all 5 tensors ----------------
__global__ __launch_bounds__(256)
void cvt_all_k(const float* __restrict__ x, const float* __restrict__ wq,
               const float* __restrict__ wk, const float* __restrict__ wv,
               const float* __restrict__ wo,
               unsigned short* __restrict__ xb, unsigned short* __restrict__ wqb,
               unsigned short* __restrict__ wkb, unsigned short* __restrict__ wvb,
               unsigned short* __restrict__ wob)
{
  const int i = blockIdx.x * 256 + threadIdx.x;      // uint4 index
  const int n0 = LTOK * DIMC / 4;
  const int nw = DIMC * DIMC / 4;
  const float* src; unsigned short* dst; int off;
  if (i < n0) { src = x; dst = xb; off = i; }
  else {
    int j = i - n0; int w = j / nw; off = j - w * nw;
    src = (w == 0) ? wq : (w == 1) ? wk : (w == 2) ? wv : wo;
    dst = (w == 0) ? wqb : (w == 1) ? wkb : (w == 2) ? wvb : wob;
  }
  float4 f = ((const float4*)src)[off];
  uint2 o;
  o.x = (unsigned int)f2bf(f.x) | ((unsigned int)f2bf(f.y) << 16);
  o.y = (unsigned int)f2bf(f.z) | ((unsigned int)f2bf(f.w) << 16);
  ((uint2*)dst)[off] = o;
}

// ---------------- NT GEMM: C[M,N] = A[M,K] * B[N,K]^T + bias ----------------
// 128x128 tile, BK=32, 512 threads = 8 waves (4x2 of 32x64 each).
// 8 waves/block doubles per-CU MFMA issue when block-starved (wo-GEMM has
// only 288 blocks -> most CUs hold a single block).
template <bool F32OUT>
__global__ __launch_bounds__(512)
void gemm_nt(const unsigned short* __restrict__ A,
             const unsigned short* __restrict__ B0,
             const unsigned short* __restrict__ B1,
             const unsigned short* __restrict__ B2,
             const float* __restrict__ bias0,
             const float* __restrict__ bias1,
             const float* __restrict__ bias2,
             void* __restrict__ o0, void* __restrict__ o1, void* __restrict__ o2)
{
  const int z = blockIdx.z;
  const unsigned short* Bw = (z == 0) ? B0 : (z == 1) ? B1 : B2;
  const float* bias = (z == 0) ? bias0 : (z == 1) ? bias1 : bias2;
  void* outp = (z == 0) ? o0 : (z == 1) ? o1 : o2;

  __shared__ __align__(16) unsigned short lA[128 * 32];
  __shared__ __align__(16) unsigned short lB[128 * 32];

  const int tid = threadIdx.x;
  const int wave = tid >> 6;          // 0..7
  const int lane = tid & 63;
  const int m0 = blockIdx.y * 128;
  const int n0 = blockIdx.x * 128;
  const int wm = (wave >> 1) * 32;    // 4 m-groups of 32
  const int wn = (wave & 1) * 64;     // 2 n-groups of 64

  f32x4 acc[2][4] = {};

  const int srow = tid >> 2;          // 0..127
  const int scol = (tid & 3) * 8;     // 0,8,16,24
  const int fr = lane & 15;
  const int fk = (lane >> 4) * 8;

  unsigned short* la = &lA[srow * 32 + scol];     // = byte offset tid*16
  unsigned short* lb = &lB[srow * 32 + scol];
  const unsigned short* ga = A  + (size_t)(m0 + srow) * DIMC + scol;
  const unsigned short* gb = Bw + (size_t)(n0 + srow) * DIMC + scol;

  for (int k0 = 0; k0 < DIMC; k0 += 32) {
    dma16(ga + k0, la);
    dma16(gb + k0, lb);
    __syncthreads();

    bf16x8 af[2], bf[4];
#pragma unroll
    for (int i = 0; i < 2; ++i)
      af[i] = *(const bf16x8*)&lA[(wm + i * 16 + fr) * 32 + fk];
#pragma unroll
    for (int j = 0; j < 4; ++j)
      bf[j] = *(const bf16x8*)&lB[(wn + j * 16 + fr) * 32 + fk];
#pragma unroll
    for (int i = 0; i < 2; ++i)
#pragma unroll
      for (int j = 0; j < 4; ++j)
        acc[i][j] = __builtin_amdgcn_mfma_f32_16x16x32_bf16(af[i], bf[j], acc[i][j], 0, 0, 0);
    __syncthreads();
  }

  const int col = lane & 15;
  const int rb = (lane >> 4) * 4;
#pragma unroll
  for (int j = 0; j < 4; ++j) {
    const int gn = n0 + wn + j * 16 + col;
    const float bv = bias[gn];
#pragma unroll
    for (int i = 0; i < 2; ++i) {
#pragma unroll
      for (int r = 0; r < 4; ++r) {
        const int gm = m0 + wm + i * 16 + rb + r;
        float val = acc[i][j][r] + bv;
        if (F32OUT)
          ((float*)outp)[(size_t)gm * DIMC + gn] = val;
        else
          ((unsigned short*)outp)[(size_t)gm * DIMC + gn] = f2bf(val);
      }
    }
  }
}

// key permutation inside each 64-key tile (4-token groups stay contiguous):
// group G (tok>>2, bits g3g2g1g0) -> G' = g3*8 + g1*4 + g0*2 + g2.
// Chosen so the PV B-operand fragment IS the softmax output registers
// (P never touches LDS). Bijection; applied identically in transpose_v.
__device__ __forceinline__ int vperm4(int G) {
  return (((G >> 3) & 1) << 3) | (((G >> 1) & 1) << 2) | ((G & 1) << 1) | ((G >> 2) & 1);
}

// ---------------- fused: rmsnorm+RoPE on q/k  AND  V transpose ----------------
// grid x: [0,2*LTOK) rope ; [2*LTOK, 2*LTOK+1152) transpose tiles
__global__ __launch_bounds__(256)
void post_qkv_k(unsigned short* __restrict__ q, unsigned short* __restrict__ k,
                const unsigned short* __restrict__ v, unsigned short* __restrict__ vt,
                const float* __restrict__ nqw, const float* __restrict__ nkw,
                const float* __restrict__ freqs)
{
  const int bx = blockIdx.x;
  const int tid = threadIdx.x;
  if (bx < 2 * LTOK) {
    const int which = bx >= LTOK;
    const int tok = bx - which * LTOK;
    unsigned short* row = (which ? k : q) + (size_t)tok * DIMC;
    const float* nw = which ? nkw : nqw;
    const float sc = which ? 1.f : (0.08838834764831845f * 1.4426950408889634f);
    const int base = tid * 6;

    float vv[6];
    float ss = 0.f;
#pragma unroll
    for (int j = 0; j < 6; ++j) {
      vv[j] = bf2f(row[base + j]);
      ss += vv[j] * vv[j];
    }
#pragma unroll
    for (int off = 1; off < 64; off <<= 1) ss += __shfl_xor(ss, off);
    __shared__ float wsum[4];
    if ((tid & 63) == 0) wsum[tid >> 6] = ss;
    __syncthreads();
    const float total = wsum[0] + wsum[1] + wsum[2] + wsum[3];
    const float rms = rsqrtf(total * (1.f / DIMC) + 1e-6f);

    const int f = tok / FS;
    const int rem = tok - f * FS;
    const int h = rem / 24;
    const int w = rem - h * 24;

#pragma unroll
    for (int pp = 0; pp < 3; ++pp) {
      const int P = (base >> 1) + pp;
      const int p = P & 63;
      const int t = (p < 22) ? f : ((p < 43) ? h : w);
      const float fre = freqs[t * 128 + p * 2];
      const float fim = freqs[t * 128 + p * 2 + 1];
      const float e = vv[2 * pp]     * rms * nw[base + 2 * pp];
      const float o = vv[2 * pp + 1] * rms * nw[base + 2 * pp + 1];
      row[base + 2 * pp]     = f2bf((e * fre - o * fim) * sc);
      row[base + 2 * pp + 1] = f2bf((e * fim + o * fre) * sc);
    }
  } else {
    // V transpose with per-64-block key permutation: vt[d][64b+pi(i)] = v[64b+i][d]
    const int c0 = bx - 2 * LTOK;          // 0..1151
    const int tb = (c0 % 48) * 64;
    const int db = (c0 / 48) * 64;
    __shared__ __align__(16) unsigned short t[64 * 72];  // [dim][tok]
#pragma unroll
    for (int it = 0; it < 2; ++it) {
      int c = tid + it * 256;
      int tok = c >> 3, dc = (c & 7) * 8;
      uint4 val = *(const uint4*)(v + (size_t)(tb + tok) * DIMC + db + dc);
      unsigned short tmp[8];
      *(uint4*)tmp = val;
#pragma unroll
      for (int j = 0; j < 8; ++j) t[(dc + j) * 72 + tok] = tmp[j];
    }
    __syncthreads();
#pragma unroll
    for (int it = 0; it < 4; ++it) {
      int c = tid + it * 256;              // 0..1023
      int d = c >> 4, G = c & 15;          // 4-token group
      *(uint2*)(vt + ((size_t)db + d) * LTOK + tb + vperm4(G) * 4) =
          *(const uint2*)&t[d * 72 + G * 4];
    }
  }
}

// ---------------- MFMA flash attention, S^T layout, split-K for heavy rows ----
// grid 936: bid<720 heavy (qb 18..47, 2 chunks), else light (qb 0..17, 1 chunk).
// S^T = K*Q^T so each lane owns ONE query: softmax m/l per-lane scalars.
// P stays in registers: V's key order is pre-permuted (vperm4) so that the
// PV B-operand fragment for step s is exactly {P[2s][0..1],P[2s+1][0..1]} of
// this lane. Named uint scalars everywhere (R2/R3 lesson: arrays fail SROA).
// LDS 35840 B -> 4 blocks/CU with __launch_bounds__(256,4); VGPR ~70 << 128.
__global__ __launch_bounds__(256, 4)
void attn_flash(const unsigned short* __restrict__ q,
                const unsigned short* __restrict__ k,
                const unsigned short* __restrict__ vt,
                unsigned short* __restrict__ ab,
                float* __restrict__ Opart,
                float* __restrict__ mlbuf)
{
  const int bid = blockIdx.x;
  int qb, head, chunk, nchunks;
  if (bid < 720) { const int hb = bid >> 1; qb = 47 - hb / 12; head = hb % 12; chunk = bid & 1; nchunks = 2; }
  else           { const int lb = bid - 720; qb = 17 - lb / 12; head = lb % 12; chunk = 0; nchunks = 1; }

  const int q0 = qb * 64;
  const int qf = qb / 6;
  const int kend = (qf + 1) * FS;
  const int s2 = kend - MAXATTN;
  const bool two = (s2 > FS);
  const int nt1 = (two ? FS : kend) >> 6;
  const int nt  = nt1 + (two ? (MAXATTN >> 6) : 0);
  const int half = nt / nchunks;               // nt even for all 2-chunk rows
  const int tstart = chunk * half, tend = tstart + half;

  const int tid = threadIdx.x;
  const int wave = tid >> 6, lane = tid & 63;
  const int col = lane & 15;       // this lane's query (within wave tile)
  const int g = lane >> 4;         // k-slice group
  const int g4 = g * 4;            // C-layout row base

  __shared__ __align__(16) unsigned short Kl[64 * 136];   // [key][dim]
  __shared__ __align__(16) unsigned short Vtl[128 * 72];  // [d][key-permuted]

  // Q fragments (B operand): B[n=q=col][k=dim slice]
  bf16x8 qfrag[4];
  {
    const unsigned short* qrow = q + (size_t)(q0 + wave * 16 + col) * DIMC + head * HD;
#pragma unroll
    for (int kk = 0; kk < 4; ++kk)
      qfrag[kk] = *(const bf16x8*)(qrow + kk * 32 + g * 8);
  }

  f32x4 oacc[8] = {};    // O^T: col=q, row=d
  float m = -3.0e38f, l = 0.f;

  // per-thread staging bases (compile-time-constant offsets between quarters)
  const unsigned short* kgb = k  + (size_t)(tid >> 4) * DIMC + head * HD + (tid & 15) * 8;
  const unsigned short* vgb = vt + ((size_t)head * HD + (tid >> 3)) * LTOK + (tid & 7) * 8;
  unsigned short* kls = &Kl[(tid >> 4) * 136 + (tid & 15) * 8];
  unsigned short* vls = &Vtl[(tid >> 3) * 72 + (tid & 7) * 8];

  uint4 kr0, kr1, kr2, kr3, vr0, vr1, vr2, vr3;
  {
    const int kb = (tstart < nt1) ? tstart * 64 : s2 + (tstart - nt1) * 64;
    const unsigned short* kp = kgb + (size_t)kb * DIMC;
    kr0 = *(const uint4*)(kp);
    kr1 = *(const uint4*)(kp + (size_t)16 * DIMC);
    kr2 = *(const uint4*)(kp + (size_t)32 * DIMC);
    kr3 = *(const uint4*)(kp + (size_t)48 * DIMC);
    const unsigned short* vp = vgb + kb;
    vr0 = *(const uint4*)(vp);
    vr1 = *(const uint4*)(vp + (size_t)32 * LTOK);
    vr2 = *(const uint4*)(vp + (size_t)64 * LTOK);
    vr3 = *(const uint4*)(vp + (size_t)96 * LTOK);
  }

  for (int t = tstart; t < tend; ++t) {
    *(uint4*)(kls)            = kr0;
    *(uint4*)(kls + 16 * 136) = kr1;
    *(uint4*)(kls + 32 * 136) = kr2;
    *(uint4*)(kls + 48 * 136) = kr3;
    *(uint4*)(vls)            = vr0;
    *(uint4*)(vls + 32 * 72)  = vr1;
    *(uint4*)(vls + 64 * 72)  = vr2;
    *(uint4*)(vls + 96 * 72)  = vr3;
    __syncthreads();

    if (t + 1 < tend) {   // prefetch next tile; overlaps with compute below
      const int kb = (t + 1 < nt1) ? (t + 1) * 64 : s2 + (t + 1 - nt1) * 64;
      const unsigned short* kp = kgb + (size_t)kb * DIMC;
      kr0 = *(const uint4*)(kp);
      kr1 = *(const uint4*)(kp + (size_t)16 * DIMC);
      kr2 = *(const uint4*)(kp + (size_t)32 * DIMC);
      kr3 = *(const uint4*)(kp + (size_t)48 * DIMC);
      const unsigned short* vp = vgb + kb;
      vr0 = *(const uint4*)(vp);
      vr1 = *(const uint4*)(vp + (size_t)32 * LTOK);
      vr2 = *(const uint4*)(vp + (size_t)64 * LTOK);
      vr3 = *(const uint4*)(vp + (size_t)96 * LTOK);
    }

    // S^T = K Q^T : C row = key (16kt + g4+r), col = q
    f32x4 s[4] = {};
#pragma unroll
    for (int kt = 0; kt < 4; ++kt)
#pragma unroll
      for (int kk = 0; kk < 4; ++kk) {
        bf16x8 kfr = *(const bf16x8*)&Kl[(kt * 16 + col) * 136 + kk * 32 + g * 8];
        s[kt] = __builtin_amdgcn_mfma_f32_16x16x32_bf16(kfr, qfrag[kk], s[kt], 0, 0, 0);
      }

    // online softmax: per-lane (q=col); 16 in-lane values + 2 shuffle hops
    float mx = s[0][0];
#pragma unroll
    for (int kt = 0; kt < 4; ++kt)
#pragma unroll
      for (int r = 0; r < 4; ++r) mx = fmaxf(mx, s[kt][r]);
    mx = fmaxf(mx, __shfl_xor(mx, 16));
    mx = fmaxf(mx, __shfl_xor(mx, 32));
    const float mn = fmaxf(m, mx);
    const float al = exp2f(m - mn);
    m = mn;
    float rs = 0.f;
    unsigned int P00, P01, P10, P11, P20, P21, P30, P31;
#define DOKT(KT, PA, PB)                                      \
    {                                                         \
      const unsigned short p0 = f2bf(exp2f(s[KT][0] - m));    \
      const unsigned short p1 = f2bf(exp2f(s[KT][1] - m));    \
      const unsigned short p2 = f2bf(exp2f(s[KT][2] - m));    \
      const unsigned short p3 = f2bf(exp2f(s[KT][3] - m));    \
      rs += bf2f(p0) + bf2f(p1) + bf2f(p2) + bf2f(p3);        \
      PA = (unsigned int)p0 | ((unsigned int)p1 << 16);       \
      PB = (unsigned int)p2 | ((unsigned int)p3 << 16);       \
    }
    DOKT(0, P00, P01)
    DOKT(1, P10, P11)
    DOKT(2, P20, P21)
    DOKT(3, P30, P31)
#undef DOKT
    rs += __shfl_xor(rs, 16);
    rs += __shfl_xor(rs, 32);
    l = l * al + rs;
#pragma unroll
    for (int dt = 0; dt < 8; ++dt) oacc[dt] *= al;

    // O^T += V^T P^T : A = Vtl rows (d, permuted key order), B = P regs.
    // With vperm4 baked into vt, step s's B frag = {P[2s][*], P[2s+1][*]}.
    union { uint4 u; bf16x8 v; } pf0, pf1;
    pf0.u.x = P00; pf0.u.y = P01; pf0.u.z = P10; pf0.u.w = P11;
    pf1.u.x = P20; pf1.u.y = P21; pf1.u.z = P30; pf1.u.w = P31;
#pragma unroll
    for (int dt = 0; dt < 8; ++dt) {
      bf16x8 vf0 = *(const bf16x8*)&Vtl[(dt * 16 + col) * 72 + g * 8];
      oacc[dt] = __builtin_amdgcn_mfma_f32_16x16x32_bf16(vf0, pf0.v, oacc[dt], 0, 0, 0);
    }
#pragma unroll
    for (int dt = 0; dt < 8; ++dt) {
      bf16x8 vf1 = *(const bf16x8*)&Vtl[(dt * 16 + col) * 72 + 32 + g * 8];
      oacc[dt] = __builtin_amdgcn_mfma_f32_16x16x32_bf16(vf1, pf1.v, oacc[dt], 0, 0, 0);
    }
    __syncthreads();
  }

  if (nchunks == 1) {
    const float linv = 1.f / l;
    unsigned short* orow = ab + (size_t)(q0 + wave * 16 + col) * DIMC + head * HD;
#pragma unroll
    for (int dt = 0; dt < 8; ++dt) {
      uint2 pk;
      pk.x = (unsigned int)f2bf(oacc[dt][0] * linv) | ((unsigned int)f2bf(oacc[dt][1] * linv) << 16);
      pk.y = (unsigned int)f2bf(oacc[dt][2] * linv) | ((unsigned int)f2bf(oacc[dt][3] * linv) << 16);
      *(uint2*)(orow + dt * 16 + g4) = pk;
    }
  } else {
    const int tokp = q0 + wave * 16 + col - HTOK;
    float* ob = Opart + ((size_t)(chunk * NHT + tokp) * HEADS + head) * HD;
#pragma unroll
    for (int dt = 0; dt < 8; ++dt)
      *(f32x4*)(ob + dt * 16 + g4) = oacc[dt];
    if (lane < 16) {
      float* mlp = mlbuf + 2 * ((size_t)(chunk * NHT + tokp) * HEADS + head);
      mlp[0] = m; mlp[1] = l;
    }
  }
}

// ---------------- merge the two K-chunks for heavy rows ----------------
__global__ __launch_bounds__(384)
void merge_k(const float* __restrict__ Opart, const float* __restrict__ mlbuf,
             unsigned short* __restrict__ ab)
{
  const int tokp = blockIdx.x;           // 0..1919
  const int tid = threadIdx.x;           // 0..383
  const int e = tid * 4;                 // elem in [0,1536)
  const int head = e >> 7;
  const size_t r0 = (size_t)tokp * DIMC + e;
  float4 o0 = *(const float4*)(Opart + r0);
  float4 o1 = *(const float4*)(Opart + (size_t)NHT * DIMC + r0);
  const float* ml0 = mlbuf + 2 * ((size_t)tokp * HEADS + head);
  const float* ml1 = mlbuf + 2 * ((size_t)(NHT + tokp) * HEADS + head);
  const float m0 = ml0[0], l0 = ml0[1], m1 = ml1[0], l1 = ml1[1];
  const float mm = fmaxf(m0, m1);
  const float a0 = exp2f(m0 - mm), a1 = exp2f(m1 - mm);
  const float inv = 1.f / (l0 * a0 + l1 * a1);
  uint2 pk;
  pk.x = (unsigned int)f2bf((o0.x * a0 + o1.x * a1) * inv) |
         ((unsigned int)f2bf((o0.y * a0 + o1.y * a1) * inv) << 16);
  pk.y = (unsigned int)f2bf((o0.z * a0 + o1.z * a1) * inv) |
         ((unsigned int)f2bf((o0.w * a0 + o1.w * a1) * inv) << 16);
  *(uint2*)(ab + (size_t)(HTOK + tokp) * DIMC + e) = pk;
}

// ---------------- launch ----------------
extern "C" void kernel_launch(void* const* d_in, const int* in_sizes, int n_in,
                              void* d_out, int out_size, void* d_ws, size_t ws_size,
                              hipStream_t stream)
{
  (void)in_sizes; (void)n_in; (void)out_size; (void)ws_size;
  const float* x     = (const float*)d_in[0];
  const float* freqs = (const float*)d_in[3];
  const float* wq    = (const float*)d_in[4];
  const float* bq    = (const float*)d_in[5];
  const float* wk    = (const float*)d_in[6];
  const float* bk    = (const float*)d_in[7];
  const float* wv    = (const float*)d_in[8];
  const float* bv    = (const float*)d_in[9];
  const float* wo    = (const float*)d_in[10];
  const float* bo    = (const float*)d_in[11];
  const float* nqw   = (const float*)d_in[12];
  const float* nkw   = (const float*)d_in[13];

  char* ws = (char*)d_ws;
  size_t off = 0;
  auto take = [&](size_t bytes) -> void* {
    void* p = ws + off; off += (bytes + 255) & ~(size_t)255; return p;
  };
  // wob first (must survive attention); xb..wvb are dead after QKV GEMM and
  // are overlaid by Opart (23,592,960 B, exact match).
  unsigned short* wob = (unsigned short*)take((size_t)DIMC * DIMC * 2);
  unsigned short* qb  = (unsigned short*)take((size_t)LTOK * DIMC * 2);
  unsigned short* kb  = (unsigned short*)take((size_t)LTOK * DIMC * 2);
  unsigned short* vb  = (unsigned short*)take((size_t)LTOK * DIMC * 2);
  unsigned short* ab  = (unsigned short*)take((size_t)LTOK * DIMC * 2);
  unsigned short* vtb = (unsigned short*)take((size_t)LTOK * DIMC * 2);
  unsigned short* xb  = (unsigned short*)take((size_t)LTOK * DIMC * 2);
  unsigned short* wqb = (unsigned short*)take((size_t)DIMC * DIMC * 2);
  unsigned short* wkb = (unsigned short*)take((size_t)DIMC * DIMC * 2);
  unsigned short* wvb = (unsigned short*)take((size_t)DIMC * DIMC * 2);
  float* mlb = (float*)take((size_t)2 * NHT * HEADS * 2 * sizeof(float));
  float* Opart = (float*)xb;   // overlays xb+wqb+wkb+wvb

  cvt_all_k<<<dim3(13824), dim3(256), 0, stream>>>(x, wq, wk, wv, wo,
                                                   xb, wqb, wkb, wvb, wob);

  gemm_nt<false><<<dim3(DIMC / 128, LTOK / 128, 3), dim3(512), 0, stream>>>(
      xb, wqb, wkb, wvb, bq, bk, bv, qb, kb, vb);

  post_qkv_k<<<dim3(2 * LTOK + 1152), dim3(256), 0, stream>>>(
      qb, kb, vb, vtb, nqw, nkw, freqs);

  attn_flash<<<dim3(936), dim3(256), 0, stream>>>(qb, kb, vtb, ab, Opart, mlb);
  merge_k<<<dim3(NHT), dim3(384), 0, stream>>>(Opart, mlb, ab);

  gemm_nt<true><<<dim3(DIMC / 128, LTOK / 128, 1), dim3(512), 0, stream>>>(
      ab, wob, wob, wob, bo, bo, bo, d_out, d_out, d_out);
}

// Round 7
// 319.437 us; speedup vs baseline: 1.0697x; 1.0697x over previous
//
#include <hip/hip_runtime.h>
#include <stdint.h>

#define DIMC 1536
#define LTOK 3072
#define HEADS 12
#define HD 128
#define FS 384            // H*W = 16*24
#define MAXATTN 1920
#define HTOK 1152         // first token with qf>=3 (2-chunk rows)
#define NHT 1920          // number of heavy tokens

typedef __attribute__((ext_vector_type(4))) float f32x4;
typedef __attribute__((ext_vector_type(8))) short bf16x8;
typedef __attribute__((ext_vector_type(4))) unsigned int u32x4;

__device__ __forceinline__ unsigned short f2bf(float f) {
  union { float f; unsigned int u; } c; c.f = f;
  unsigned int u = c.u + 0x7fffu + ((c.u >> 16) & 1u);   // RNE
  return (unsigned short)(u >> 16);
}
__device__ __forceinline__ float bf2f(unsigned short s) {
  union { unsigned int u; float f; } c; c.u = (unsigned int)s << 16; return c.f;
}

// async global->LDS DMA, 16B per lane; LDS dest must be wave-uniform base +
// lane*16 (all our staging offsets are tid*16B -> satisfied).
__device__ __forceinline__ void dma16(const void* g, void* l) {
  __builtin_amdgcn_global_load_lds(
      (const __attribute__((address_space(1))) unsigned int*)g,
      (__attribute__((address_space(3))) unsigned int*)l, 16, 0, 0);
}

// ---------------- fused fp32 -> bf16 conversion for all 5 tensors ----------------
__global__ __launch_bounds__(256)
void cvt_all_k(const float* __restrict__ x, const float* __restrict__ wq,
               const float* __restrict__ wk, const float* __restrict__ wv,
               const float* __restrict__ wo,
               unsigned short* __restrict__ xb, unsigned short* __restrict__ wqb,
               unsigned short* __restrict__ wkb, unsigned short* __restrict__ wvb,
               unsigned short* __restrict__ wob)
{
  const int i = blockIdx.x * 256 + threadIdx.x;      // uint4 index
  const int n0 = LTOK * DIMC / 4;
  const int nw = DIMC * DIMC / 4;
  const float* src; unsigned short* dst; int off;
  if (i < n0) { src = x; dst = xb; off = i; }
  else {
    int j = i - n0; int w = j / nw; off = j - w * nw;
    src = (w == 0) ? wq : (w == 1) ? wk : (w == 2) ? wv : wo;
    dst = (w == 0) ? wqb : (w == 1) ? wkb : (w == 2) ? wvb : wob;
  }
  float4 f = ((const float4*)src)[off];
  uint2 o;
  o.x = (unsigned int)f2bf(f.x) | ((unsigned int)f2bf(f.y) << 16);
  o.y = (unsigned int)f2bf(f.z) | ((unsigned int)f2bf(f.w) << 16);
  ((uint2*)dst)[off] = o;
}

// ---------------- QKV GEMM (R5-proven): 128x128 tile, BK=32, 256 thr ----------
__global__ __launch_bounds__(256)
void gemm_qkv(const unsigned short* __restrict__ A,
              const unsigned short* __restrict__ B0,
              const unsigned short* __restrict__ B1,
              const unsigned short* __restrict__ B2,
              const float* __restrict__ bias0,
              const float* __restrict__ bias1,
              const float* __restrict__ bias2,
              unsigned short* __restrict__ o0, unsigned short* __restrict__ o1,
              unsigned short* __restrict__ o2)
{
  const int z = blockIdx.z;
  const unsigned short* Bw = (z == 0) ? B0 : (z == 1) ? B1 : B2;
  const float* bias = (z == 0) ? bias0 : (z == 1) ? bias1 : bias2;
  unsigned short* outp = (z == 0) ? o0 : (z == 1) ? o1 : o2;

  __shared__ __align__(16) unsigned short lA[128 * 32];
  __shared__ __align__(16) unsigned short lB[128 * 32];

  const int tid = threadIdx.x;
  const int wave = tid >> 6;
  const int lane = tid & 63;
  const int m0 = blockIdx.y * 128;
  const int n0 = blockIdx.x * 128;
  const int wm = (wave >> 1) * 64;
  const int wn = (wave & 1) * 64;

  f32x4 acc[4][4] = {};

  const int srow = tid >> 2;         // 0..63
  const int scol = (tid & 3) * 8;    // 0,8,16,24
  const int fr = lane & 15;
  const int fk = (lane >> 4) * 8;

  unsigned short* la0 = &lA[srow * 32 + scol];
  unsigned short* la1 = &lA[(srow + 64) * 32 + scol];
  unsigned short* lb0 = &lB[srow * 32 + scol];
  unsigned short* lb1 = &lB[(srow + 64) * 32 + scol];
  const unsigned short* ga0 = A  + (size_t)(m0 + srow)      * DIMC + scol;
  const unsigned short* ga1 = A  + (size_t)(m0 + srow + 64) * DIMC + scol;
  const unsigned short* gb0 = Bw + (size_t)(n0 + srow)      * DIMC + scol;
  const unsigned short* gb1 = Bw + (size_t)(n0 + srow + 64) * DIMC + scol;

  for (int k0 = 0; k0 < DIMC; k0 += 32) {
    dma16(ga0 + k0, la0);
    dma16(ga1 + k0, la1);
    dma16(gb0 + k0, lb0);
    dma16(gb1 + k0, lb1);
    __syncthreads();

    bf16x8 af[4], bf[4];
#pragma unroll
    for (int i = 0; i < 4; ++i)
      af[i] = *(const bf16x8*)&lA[(wm + i * 16 + fr) * 32 + fk];
#pragma unroll
    for (int j = 0; j < 4; ++j)
      bf[j] = *(const bf16x8*)&lB[(wn + j * 16 + fr) * 32 + fk];
#pragma unroll
    for (int i = 0; i < 4; ++i)
#pragma unroll
      for (int j = 0; j < 4; ++j)
        acc[i][j] = __builtin_amdgcn_mfma_f32_16x16x32_bf16(af[i], bf[j], acc[i][j], 0, 0, 0);
    __syncthreads();
  }

  const int col = lane & 15;
  const int rb = (lane >> 4) * 4;
#pragma unroll
  for (int j = 0; j < 4; ++j) {
    const int gn = n0 + wn + j * 16 + col;
    const float bv = bias[gn];
#pragma unroll
    for (int i = 0; i < 4; ++i)
#pragma unroll
      for (int r = 0; r < 4; ++r) {
        const int gm = m0 + wm + i * 16 + rb + r;
        outp[(size_t)gm * DIMC + gn] = f2bf(acc[i][j][r] + bv);
      }
  }
}

// ---------------- wo GEMM: 512 thr / 8 waves (better when block-starved) ------
__global__ __launch_bounds__(512)
void gemm_wo(const unsigned short* __restrict__ A,
             const unsigned short* __restrict__ Bw,
             const float* __restrict__ bias,
             float* __restrict__ outp)
{
  __shared__ __align__(16) unsigned short lA[128 * 32];
  __shared__ __align__(16) unsigned short lB[128 * 32];

  const int tid = threadIdx.x;
  const int wave = tid >> 6;          // 0..7
  const int lane = tid & 63;
  const int m0 = blockIdx.y * 128;
  const int n0 = blockIdx.x * 128;
  const int wm = (wave >> 1) * 32;    // 4 m-groups of 32
  const int wn = (wave & 1) * 64;     // 2 n-groups of 64

  f32x4 acc[2][4] = {};

  const int srow = tid >> 2;          // 0..127
  const int scol = (tid & 3) * 8;
  const int fr = lane & 15;
  const int fk = (lane >> 4) * 8;

  unsigned short* la = &lA[srow * 32 + scol];
  unsigned short* lb = &lB[srow * 32 + scol];
  const unsigned short* ga = A  + (size_t)(m0 + srow) * DIMC + scol;
  const unsigned short* gb = Bw + (size_t)(n0 + srow) * DIMC + scol;

  for (int k0 = 0; k0 < DIMC; k0 += 32) {
    dma16(ga + k0, la);
    dma16(gb + k0, lb);
    __syncthreads();

    bf16x8 af[2], bf[4];
#pragma unroll
    for (int i = 0; i < 2; ++i)
      af[i] = *(const bf16x8*)&lA[(wm + i * 16 + fr) * 32 + fk];
#pragma unroll
    for (int j = 0; j < 4; ++j)
      bf[j] = *(const bf16x8*)&lB[(wn + j * 16 + fr) * 32 + fk];
#pragma unroll
    for (int i = 0; i < 2; ++i)
#pragma unroll
      for (int j = 0; j < 4; ++j)
        acc[i][j] = __builtin_amdgcn_mfma_f32_16x16x32_bf16(af[i], bf[j], acc[i][j], 0, 0, 0);
    __syncthreads();
  }

  const int col = lane & 15;
  const int rb = (lane >> 4) * 4;
#pragma unroll
  for (int j = 0; j < 4; ++j) {
    const int gn = n0 + wn + j * 16 + col;
    const float bv = bias[gn];
#pragma unroll
    for (int i = 0; i < 2; ++i)
#pragma unroll
      for (int r = 0; r < 4; ++r) {
        const int gm = m0 + wm + i * 16 + rb + r;
        outp[(size_t)gm * DIMC + gn] = acc[i][j][r] + bv;
      }
  }
}

// key permutation inside each 64-key tile (4-token groups stay contiguous):
// group G bits (g3 g2 g1 g0) -> G' = g3*8 + g1*4 + g0*2 + g2, chosen so the
// PV B-operand fragment IS the softmax output registers (P never in LDS).
__device__ __forceinline__ int vperm4(int G) {
  return (((G >> 3) & 1) << 3) | (((G >> 1) & 1) << 2) | ((G & 1) << 1) | ((G >> 2) & 1);
}

// ---------------- fused: rmsnorm+RoPE on q/k  AND  V transpose ----------------
__global__ __launch_bounds__(256)
void post_qkv_k(unsigned short* __restrict__ q, unsigned short* __restrict__ k,
                const unsigned short* __restrict__ v, unsigned short* __restrict__ vt,
                const float* __restrict__ nqw, const float* __restrict__ nkw,
                const float* __restrict__ freqs)
{
  const int bx = blockIdx.x;
  const int tid = threadIdx.x;
  if (bx < 2 * LTOK) {
    const int which = bx >= LTOK;
    const int tok = bx - which * LTOK;
    unsigned short* row = (which ? k : q) + (size_t)tok * DIMC;
    const float* nw = which ? nkw : nqw;
    const float sc = which ? 1.f : (0.08838834764831845f * 1.4426950408889634f);
    const int base = tid * 6;

    float vv[6];
    float ss = 0.f;
#pragma unroll
    for (int j = 0; j < 6; ++j) {
      vv[j] = bf2f(row[base + j]);
      ss += vv[j] * vv[j];
    }
#pragma unroll
    for (int off = 1; off < 64; off <<= 1) ss += __shfl_xor(ss, off);
    __shared__ float wsum[4];
    if ((tid & 63) == 0) wsum[tid >> 6] = ss;
    __syncthreads();
    const float total = wsum[0] + wsum[1] + wsum[2] + wsum[3];
    const float rms = rsqrtf(total * (1.f / DIMC) + 1e-6f);

    const int f = tok / FS;
    const int rem = tok - f * FS;
    const int h = rem / 24;
    const int w = rem - h * 24;

#pragma unroll
    for (int pp = 0; pp < 3; ++pp) {
      const int P = (base >> 1) + pp;
      const int p = P & 63;
      const int t = (p < 22) ? f : ((p < 43) ? h : w);
      const float fre = freqs[t * 128 + p * 2];
      const float fim = freqs[t * 128 + p * 2 + 1];
      const float e = vv[2 * pp]     * rms * nw[base + 2 * pp];
      const float o = vv[2 * pp + 1] * rms * nw[base + 2 * pp + 1];
      row[base + 2 * pp]     = f2bf((e * fre - o * fim) * sc);
      row[base + 2 * pp + 1] = f2bf((e * fim + o * fre) * sc);
    }
  } else {
    // V transpose with per-64-block key permutation: vt[d][64b+pi(i)] = v[64b+i][d]
    const int c0 = bx - 2 * LTOK;          // 0..1151
    const int tb = (c0 % 48) * 64;
    const int db = (c0 / 48) * 64;
    __shared__ __align__(16) unsigned short t[64 * 72];  // [dim][tok]
#pragma unroll
    for (int it = 0; it < 2; ++it) {
      int c = tid + it * 256;
      int tok = c >> 3, dc = (c & 7) * 8;
      uint4 val = *(const uint4*)(v + (size_t)(tb + tok) * DIMC + db + dc);
      unsigned short tmp[8];
      *(uint4*)tmp = val;
#pragma unroll
      for (int j = 0; j < 8; ++j) t[(dc + j) * 72 + tok] = tmp[j];
    }
    __syncthreads();
#pragma unroll
    for (int it = 0; it < 4; ++it) {
      int c = tid + it * 256;              // 0..1023
      int d = c >> 4, G = c & 15;          // 4-token group
      *(uint2*)(vt + ((size_t)db + d) * LTOK + tb + vperm4(G) * 4) =
          *(const uint2*)&t[d * 72 + G * 4];
    }
  }
}

// ---------------- MFMA flash attention v3 -------------------------------------
// 128 queries/block (4 waves x 2 subtiles): K/V LDS fragments are shared by
// both subtiles -> LDS reads per unit work halved. Staging via dma16 (m97
// pattern, 2 barriers/tile) into UNPADDED LDS; bank conflicts avoided by an
// XOR chunk swizzle applied on the GLOBAL source address (read row&15==col,
// so the swizzle is lane-exact on the read side). P packed from named scalars
// via __builtin_bit_cast (R6 lesson: unions alloca->scratch).
// grid 468: bid<360 heavy (qb 9..23, 2 chunks), else light (qb 0..8).
__global__ __launch_bounds__(256, 3)
void attn_flash(const unsigned short* __restrict__ q,
                const unsigned short* __restrict__ k,
                const unsigned short* __restrict__ vt,
                unsigned short* __restrict__ ab,
                float* __restrict__ Opart,
                float* __restrict__ mlbuf)
{
  const int bid = blockIdx.x;
  int qb, head, chunk, nchunks;
  if (bid < 360) { const int hb = bid >> 1; qb = 23 - hb / 12; head = hb % 12; chunk = bid & 1; nchunks = 2; }
  else           { const int lb = bid - 360; qb = 8 - lb / 12; head = lb % 12; chunk = 0; nchunks = 1; }

  const int q0 = qb * 128;              // 128 divides 384 -> block in one frame
  const int qf = qb / 3;
  const int kend = (qf + 1) * FS;
  const int s2 = kend - MAXATTN;
  const bool two = (s2 > FS);
  const int nt1 = (two ? FS : kend) >> 6;
  const int nt  = nt1 + (two ? (MAXATTN >> 6) : 0);
  const int half = nt / nchunks;        // even split for all 2-chunk rows
  const int tstart = chunk * half, tend = tstart + half;

  const int tid = threadIdx.x;
  const int wave = tid >> 6, lane = tid & 63;
  const int col = lane & 15;
  const int g = lane >> 4;
  const int g4 = g * 4;

  __shared__ __align__(16) unsigned short Kl[64 * 128];   // [key][dim], XOR-swizzled chunks
  __shared__ __align__(16) unsigned short Vtl[128 * 64];  // [d][key-perm], XOR-swizzled

  // Q fragments (B operand) for this wave's two 16-q subtiles
  bf16x8 qfA[4], qfB[4];
  {
    const unsigned short* qr0 = q + (size_t)(q0 + wave * 32 + col) * DIMC + head * HD;
#pragma unroll
    for (int kk = 0; kk < 4; ++kk) {
      qfA[kk] = *(const bf16x8*)(qr0 + kk * 32 + g * 8);
      qfB[kk] = *(const bf16x8*)(qr0 + (size_t)16 * DIMC + kk * 32 + g * 8);
    }
  }

  f32x4 o0[8] = {}, o1[8] = {};
  float m0 = -3.0e38f, l0 = 0.f, m1 = -3.0e38f, l1 = 0.f;

  // staging: thread tid <-> LDS chunk tid*16B; global source XOR-swizzled
  const int krow = tid >> 4;                         // 0..15 (K row within pass)
  const int kc8  = ((tid & 15) ^ krow) * 8;
  const unsigned short* kg = k + (size_t)krow * DIMC + head * HD + kc8;
  const int vrow = tid >> 3;                         // 0..31 (V row within pass)
  const int vc8  = ((tid & 7) ^ (vrow & 7)) * 8;
  const unsigned short* vg = vt + ((size_t)head * HD + vrow) * LTOK + vc8;
  unsigned short* kl = Kl + tid * 8;
  unsigned short* vl = Vtl + tid * 8;

  for (int t = tstart; t < tend; ++t) {
    const int kb = (t < nt1) ? t * 64 : s2 + (t - nt1) * 64;
    const unsigned short* kp = kg + (size_t)kb * DIMC;
    dma16(kp,                     kl);
    dma16(kp + (size_t)16 * DIMC, kl + 16 * 128);
    dma16(kp + (size_t)32 * DIMC, kl + 32 * 128);
    dma16(kp + (size_t)48 * DIMC, kl + 48 * 128);
    const unsigned short* vp = vg + kb;
    dma16(vp,                     vl);
    dma16(vp + (size_t)32 * LTOK, vl + 32 * 64);
    dma16(vp + (size_t)64 * LTOK, vl + 64 * 64);
    dma16(vp + (size_t)96 * LTOK, vl + 96 * 64);
    __syncthreads();   // dma complete (compiler drains vmcnt before barrier)

    // S^T = K Q^T for both subtiles, sharing every K-fragment read
    f32x4 sA[4] = {}, sB[4] = {};
#pragma unroll
    for (int kt = 0; kt < 4; ++kt) {
      const unsigned short* kr = &Kl[(kt * 16 + col) * 128];
#pragma unroll
      for (int kk = 0; kk < 4; ++kk) {
        bf16x8 kfr = *(const bf16x8*)(kr + ((kk * 4 + g) ^ col) * 8);
        sA[kt] = __builtin_amdgcn_mfma_f32_16x16x32_bf16(kfr, qfA[kk], sA[kt], 0, 0, 0);
        sB[kt] = __builtin_amdgcn_mfma_f32_16x16x32_bf16(kfr, qfB[kk], sB[kt], 0, 0, 0);
      }
    }

    // ---- softmax subtile A (per-lane q=col; named P scalars) ----
    unsigned int A0, A1, A2, A3, A4, A5, A6, A7;
    float alA;
    {
      float mx = sA[0][0];
#pragma unroll
      for (int kt = 0; kt < 4; ++kt)
#pragma unroll
        for (int r = 0; r < 4; ++r) mx = fmaxf(mx, sA[kt][r]);
      mx = fmaxf(mx, __shfl_xor(mx, 16));
      mx = fmaxf(mx, __shfl_xor(mx, 32));
      const float mn = fmaxf(m0, mx);
      alA = exp2f(m0 - mn);
      m0 = mn;
      float rs = 0.f;
#define PKA(KT, PA, PB)                                        \
      {                                                        \
        const unsigned short p0 = f2bf(exp2f(sA[KT][0] - mn)); \
        const unsigned short p1 = f2bf(exp2f(sA[KT][1] - mn)); \
        const unsigned short p2 = f2bf(exp2f(sA[KT][2] - mn)); \
        const unsigned short p3 = f2bf(exp2f(sA[KT][3] - mn)); \
        rs += bf2f(p0) + bf2f(p1) + bf2f(p2) + bf2f(p3);       \
        PA = (unsigned int)p0 | ((unsigned int)p1 << 16);      \
        PB = (unsigned int)p2 | ((unsigned int)p3 << 16);      \
      }
      PKA(0, A0, A1) PKA(1, A2, A3) PKA(2, A4, A5) PKA(3, A6, A7)
#undef PKA
      rs += __shfl_xor(rs, 16);
      rs += __shfl_xor(rs, 32);
      l0 = l0 * alA + rs;
    }
    // ---- softmax subtile B ----
    unsigned int B0, B1, B2, B3, B4, B5, B6, B7;
    float alB;
    {
      float mx = sB[0][0];
#pragma unroll
      for (int kt = 0; kt < 4; ++kt)
#pragma unroll
        for (int r = 0; r < 4; ++r) mx = fmaxf(mx, sB[kt][r]);
      mx = fmaxf(mx, __shfl_xor(mx, 16));
      mx = fmaxf(mx, __shfl_xor(mx, 32));
      const float mn = fmaxf(m1, mx);
      alB = exp2f(m1 - mn);
      m1 = mn;
      float rs = 0.f;
#define PKB(KT, PA, PB)                                        \
      {                                                        \
        const unsigned short p0 = f2bf(exp2f(sB[KT][0] - mn)); \
        const unsigned short p1 = f2bf(exp2f(sB[KT][1] - mn)); \
        const unsigned short p2 = f2bf(exp2f(sB[KT][2] - mn)); \
        const unsigned short p3 = f2bf(exp2f(sB[KT][3] - mn)); \
        rs += bf2f(p0) + bf2f(p1) + bf2f(p2) + bf2f(p3);       \
        PA = (unsigned int)p0 | ((unsigned int)p1 << 16);      \
        PB = (unsigned int)p2 | ((unsigned int)p3 << 16);      \
      }
      PKB(0, B0, B1) PKB(1, B2, B3) PKB(2, B4, B5) PKB(3, B6, B7)
#undef PKB
      rs += __shfl_xor(rs, 16);
      rs += __shfl_xor(rs, 32);
      l1 = l1 * alB + rs;
    }

#pragma unroll
    for (int dt = 0; dt < 8; ++dt) { o0[dt] *= alA; o1[dt] *= alB; }

    // P fragments from named scalars via bit_cast (register-only)
    u32x4 tA0, tA1, tB0, tB1;
    tA0[0] = A0; tA0[1] = A1; tA0[2] = A2; tA0[3] = A3;
    tA1[0] = A4; tA1[1] = A5; tA1[2] = A6; tA1[3] = A7;
    tB0[0] = B0; tB0[1] = B1; tB0[2] = B2; tB0[3] = B3;
    tB1[0] = B4; tB1[1] = B5; tB1[2] = B6; tB1[3] = B7;
    const bf16x8 pfA0 = __builtin_bit_cast(bf16x8, tA0);
    const bf16x8 pfA1 = __builtin_bit_cast(bf16x8, tA1);
    const bf16x8 pfB0 = __builtin_bit_cast(bf16x8, tB0);
    const bf16x8 pfB1 = __builtin_bit_cast(bf16x8, tB1);

    // O^T += V^T P^T, sharing every V-fragment read between subtiles
    const int vx0 = (g ^ (col & 7)) * 8;         // step-0 chunk (swizzled)
    const int vx1 = ((4 + g) ^ (col & 7)) * 8;   // step-1 chunk
#pragma unroll
    for (int dt = 0; dt < 8; ++dt) {
      const unsigned short* vr = &Vtl[(dt * 16 + col) * 64];
      bf16x8 vf0 = *(const bf16x8*)(vr + vx0);
      o0[dt] = __builtin_amdgcn_mfma_f32_16x16x32_bf16(vf0, pfA0, o0[dt], 0, 0, 0);
      o1[dt] = __builtin_amdgcn_mfma_f32_16x16x32_bf16(vf0, pfB0, o1[dt], 0, 0, 0);
      bf16x8 vf1 = *(const bf16x8*)(vr + vx1);
      o0[dt] = __builtin_amdgcn_mfma_f32_16x16x32_bf16(vf1, pfA1, o0[dt], 0, 0, 0);
      o1[dt] = __builtin_amdgcn_mfma_f32_16x16x32_bf16(vf1, pfB1, o1[dt], 0, 0, 0);
    }
    __syncthreads();   // all reads done before next tile's dma overwrites
  }

  const int qrow0 = q0 + wave * 32 + col;       // subtile-A query token
  if (nchunks == 1) {
    const float i0 = 1.f / l0, i1 = 1.f / l1;
    unsigned short* or0 = ab + (size_t)qrow0 * DIMC + head * HD;
    unsigned short* or1 = or0 + (size_t)16 * DIMC;
#pragma unroll
    for (int dt = 0; dt < 8; ++dt) {
      uint2 pk;
      pk.x = (unsigned int)f2bf(o0[dt][0] * i0) | ((unsigned int)f2bf(o0[dt][1] * i0) << 16);
      pk.y = (unsigned int)f2bf(o0[dt][2] * i0) | ((unsigned int)f2bf(o0[dt][3] * i0) << 16);
      *(uint2*)(or0 + dt * 16 + g4) = pk;
      pk.x = (unsigned int)f2bf(o1[dt][0] * i1) | ((unsigned int)f2bf(o1[dt][1] * i1) << 16);
      pk.y = (unsigned int)f2bf(o1[dt][2] * i1) | ((unsigned int)f2bf(o1[dt][3] * i1) << 16);
      *(uint2*)(or1 + dt * 16 + g4) = pk;
    }
  } else {
    const int tokp0 = qrow0 - HTOK;
    float* ob0 = Opart + ((size_t)(chunk * NHT + tokp0) * HEADS + head) * HD;
    float* ob1 = Opart + ((size_t)(chunk * NHT + tokp0 + 16) * HEADS + head) * HD;
#pragma unroll
    for (int dt = 0; dt < 8; ++dt) {
      *(f32x4*)(ob0 + dt * 16 + g4) = o0[dt];
      *(f32x4*)(ob1 + dt * 16 + g4) = o1[dt];
    }
    if (lane < 16) {
      float* mlp0 = mlbuf + 2 * ((size_t)(chunk * NHT + tokp0) * HEADS + head);
      float* mlp1 = mlbuf + 2 * ((size_t)(chunk * NHT + tokp0 + 16) * HEADS + head);
      mlp0[0] = m0; mlp0[1] = l0;
      mlp1[0] = m1; mlp1[1] = l1;
    }
  }
}

// ---------------- merge the two K-chunks for heavy rows ----------------
__global__ __launch_bounds__(384)
void merge_k(const float* __restrict__ Opart, const float* __restrict__ mlbuf,
             unsigned short* __restrict__ ab)
{
  const int tokp = blockIdx.x;           // 0..1919
  const int tid = threadIdx.x;           // 0..383
  const int e = tid * 4;                 // elem in [0,1536)
  const int head = e >> 7;
  const size_t r0 = (size_t)tokp * DIMC + e;
  float4 o0 = *(const float4*)(Opart + r0);
  float4 o1 = *(const float4*)(Opart + (size_t)NHT * DIMC + r0);
  const float* ml0 = mlbuf + 2 * ((size_t)tokp * HEADS + head);
  const float* ml1 = mlbuf + 2 * ((size_t)(NHT + tokp) * HEADS + head);
  const float m0 = ml0[0], l0 = ml0[1], m1 = ml1[0], l1 = ml1[1];
  const float mm = fmaxf(m0, m1);
  const float a0 = exp2f(m0 - mm), a1 = exp2f(m1 - mm);
  const float inv = 1.f / (l0 * a0 + l1 * a1);
  uint2 pk;
  pk.x = (unsigned int)f2bf((o0.x * a0 + o1.x * a1) * inv) |
         ((unsigned int)f2bf((o0.y * a0 + o1.y * a1) * inv) << 16);
  pk.y = (unsigned int)f2bf((o0.z * a0 + o1.z * a1) * inv) |
         ((unsigned int)f2bf((o0.w * a0 + o1.w * a1) * inv) << 16);
  *(uint2*)(ab + (size_t)(HTOK + tokp) * DIMC + e) = pk;
}

// ---------------- launch ----------------
extern "C" void kernel_launch(void* const* d_in, const int* in_sizes, int n_in,
                              void* d_out, int out_size, void* d_ws, size_t ws_size,
                              hipStream_t stream)
{
  (void)in_sizes; (void)n_in; (void)out_size; (void)ws_size;
  const float* x     = (const float*)d_in[0];
  const float* freqs = (const float*)d_in[3];
  const float* wq    = (const float*)d_in[4];
  const float* bq    = (const float*)d_in[5];
  const float* wk    = (const float*)d_in[6];
  const float* bk    = (const float*)d_in[7];
  const float* wv    = (const float*)d_in[8];
  const float* bv    = (const float*)d_in[9];
  const float* wo    = (const float*)d_in[10];
  const float* bo    = (const float*)d_in[11];
  const float* nqw   = (const float*)d_in[12];
  const float* nkw   = (const float*)d_in[13];

  char* ws = (char*)d_ws;
  size_t off = 0;
  auto take = [&](size_t bytes) -> void* {
    void* p = ws + off; off += (bytes + 255) & ~(size_t)255; return p;
  };
  // wob first (must survive attention); xb..wvb are dead after QKV GEMM and
  // are overlaid by Opart (23,592,960 B, exact match).
  unsigned short* wob = (unsigned short*)take((size_t)DIMC * DIMC * 2);
  unsigned short* qb  = (unsigned short*)take((size_t)LTOK * DIMC * 2);
  unsigned short* kb  = (unsigned short*)take((size_t)LTOK * DIMC * 2);
  unsigned short* vb  = (unsigned short*)take((size_t)LTOK * DIMC * 2);
  unsigned short* ab  = (unsigned short*)take((size_t)LTOK * DIMC * 2);
  unsigned short* vtb = (unsigned short*)take((size_t)LTOK * DIMC * 2);
  unsigned short* xb  = (unsigned short*)take((size_t)LTOK * DIMC * 2);
  unsigned short* wqb = (unsigned short*)take((size_t)DIMC * DIMC * 2);
  unsigned short* wkb = (unsigned short*)take((size_t)DIMC * DIMC * 2);
  unsigned short* wvb = (unsigned short*)take((size_t)DIMC * DIMC * 2);
  float* mlb = (float*)take((size_t)2 * NHT * HEADS * 2 * sizeof(float));
  float* Opart = (float*)xb;   // overlays xb+wqb+wkb+wvb

  cvt_all_k<<<dim3(13824), dim3(256), 0, stream>>>(x, wq, wk, wv, wo,
                                                   xb, wqb, wkb, wvb, wob);

  gemm_qkv<<<dim3(DIMC / 128, LTOK / 128, 3), dim3(256), 0, stream>>>(
      xb, wqb, wkb, wvb, bq, bk, bv, qb, kb, vb);

  post_qkv_k<<<dim3(2 * LTOK + 1152), dim3(256), 0, stream>>>(
      qb, kb, vb, vtb, nqw, nkw, freqs);

  attn_flash<<<dim3(468), dim3(256), 0, stream>>>(qb, kb, vtb, ab, Opart, mlb);
  merge_k<<<dim3(NHT), dim3(384), 0, stream>>>(Opart, mlb, ab);

  gemm_wo<<<dim3(DIMC / 128, LTOK / 128), dim3(512), 0, stream>>>(
      ab, wob, bo, (float*)d_out);
}

// Round 8
// 318.465 us; speedup vs baseline: 1.0729x; 1.0031x over previous
//
#include <hip/hip_runtime.h>
#include <stdint.h>

#define DIMC 1536
#define LTOK 3072
#define HEADS 12
#define HD 128
#define FS 384            // H*W = 16*24
#define MAXATTN 1920
#define HTOK 1152         // first token with qf>=3 (2-chunk rows)
#define NHT 1920          // number of heavy tokens

typedef __attribute__((ext_vector_type(4))) float f32x4;
typedef __attribute__((ext_vector_type(8))) short bf16x8;
typedef __attribute__((ext_vector_type(4))) unsigned int u32x4;

__device__ __forceinline__ unsigned short f2bf(float f) {
  union { float f; unsigned int u; } c; c.f = f;
  unsigned int u = c.u + 0x7fffu + ((c.u >> 16) & 1u);   // RNE
  return (unsigned short)(u >> 16);
}
__device__ __forceinline__ float bf2f(unsigned short s) {
  union { unsigned int u; float f; } c; c.u = (unsigned int)s << 16; return c.f;
}

// async global->LDS DMA, 16B per lane; LDS dest must be wave-uniform base +
// lane*16 (all our staging offsets are tid*16B -> satisfied).
__device__ __forceinline__ void dma16(const void* g, void* l) {
  __builtin_amdgcn_global_load_lds(
      (const __attribute__((address_space(1))) unsigned int*)g,
      (__attribute__((address_space(3))) unsigned int*)l, 16, 0, 0);
}

// ---------------- fused fp32 -> bf16 conversion for all 5 tensors ----------------
__global__ __launch_bounds__(256)
void cvt_all_k(const float* __restrict__ x, const float* __restrict__ wq,
               const float* __restrict__ wk, const float* __restrict__ wv,
               const float* __restrict__ wo,
               unsigned short* __restrict__ xb, unsigned short* __restrict__ wqb,
               unsigned short* __restrict__ wkb, unsigned short* __restrict__ wvb,
               unsigned short* __restrict__ wob)
{
  const int i = blockIdx.x * 256 + threadIdx.x;      // uint4 index
  const int n0 = LTOK * DIMC / 4;
  const int nw = DIMC * DIMC / 4;
  const float* src; unsigned short* dst; int off;
  if (i < n0) { src = x; dst = xb; off = i; }
  else {
    int j = i - n0; int w = j / nw; off = j - w * nw;
    src = (w == 0) ? wq : (w == 1) ? wk : (w == 2) ? wv : wo;
    dst = (w == 0) ? wqb : (w == 1) ? wkb : (w == 2) ? wvb : wob;
  }
  float4 f = ((const float4*)src)[off];
  uint2 o;
  o.x = (unsigned int)f2bf(f.x) | ((unsigned int)f2bf(f.y) << 16);
  o.y = (unsigned int)f2bf(f.z) | ((unsigned int)f2bf(f.w) << 16);
  ((uint2*)dst)[off] = o;
}

// ---------------- QKV GEMM: 128x128 tile, BK=32, 256 thr ----------------------
// Double-buffered LDS; next tile's global_load_lds issued right AFTER the
// barrier so the DMA overlaps the whole compute phase (one barrier/iter).
#define GBUF (128 * 32)
__global__ __launch_bounds__(256)
void gemm_qkv(const unsigned short* __restrict__ A,
              const unsigned short* __restrict__ B0,
              const unsigned short* __restrict__ B1,
              const unsigned short* __restrict__ B2,
              const float* __restrict__ bias0,
              const float* __restrict__ bias1,
              const float* __restrict__ bias2,
              unsigned short* __restrict__ o0, unsigned short* __restrict__ o1,
              unsigned short* __restrict__ o2)
{
  const int z = blockIdx.z;
  const unsigned short* Bw = (z == 0) ? B0 : (z == 1) ? B1 : B2;
  const float* bias = (z == 0) ? bias0 : (z == 1) ? bias1 : bias2;
  unsigned short* outp = (z == 0) ? o0 : (z == 1) ? o1 : o2;

  __shared__ __align__(16) unsigned short lA[2 * GBUF];
  __shared__ __align__(16) unsigned short lB[2 * GBUF];

  const int tid = threadIdx.x;
  const int wave = tid >> 6;
  const int lane = tid & 63;
  const int m0 = blockIdx.y * 128;
  const int n0 = blockIdx.x * 128;
  const int wm = (wave >> 1) * 64;
  const int wn = (wave & 1) * 64;

  f32x4 acc[4][4] = {};

  const int srow = tid >> 2;         // 0..63
  const int scol = (tid & 3) * 8;    // 0,8,16,24
  const int fr = lane & 15;
  const int fk = (lane >> 4) * 8;

  unsigned short* laS = lA + srow * 32 + scol;
  unsigned short* lbS = lB + srow * 32 + scol;
  const unsigned short* ga0 = A  + (size_t)(m0 + srow)      * DIMC + scol;
  const unsigned short* ga1 = A  + (size_t)(m0 + srow + 64) * DIMC + scol;
  const unsigned short* gb0 = Bw + (size_t)(n0 + srow)      * DIMC + scol;
  const unsigned short* gb1 = Bw + (size_t)(n0 + srow + 64) * DIMC + scol;

  // prime buffer 0
  dma16(ga0, laS);
  dma16(ga1, laS + 64 * 32);
  dma16(gb0, lbS);
  dma16(gb1, lbS + 64 * 32);

  for (int t = 0; t < 48; ++t) {
    const int cur = (t & 1) * GBUF;
    __syncthreads();                 // drains dma(t); joins reads of buf(t-1)
    if (t < 47) {                    // prefetch t+1 overlaps compute(t)
      const int nxt = GBUF - cur;
      const int k0n = (t + 1) * 32;
      dma16(ga0 + k0n, laS + nxt);
      dma16(ga1 + k0n, laS + nxt + 64 * 32);
      dma16(gb0 + k0n, lbS + nxt);
      dma16(gb1 + k0n, lbS + nxt + 64 * 32);
    }

    bf16x8 af[4], bf[4];
#pragma unroll
    for (int i = 0; i < 4; ++i)
      af[i] = *(const bf16x8*)&lA[cur + (wm + i * 16 + fr) * 32 + fk];
#pragma unroll
    for (int j = 0; j < 4; ++j)
      bf[j] = *(const bf16x8*)&lB[cur + (wn + j * 16 + fr) * 32 + fk];
#pragma unroll
    for (int i = 0; i < 4; ++i)
#pragma unroll
      for (int j = 0; j < 4; ++j)
        acc[i][j] = __builtin_amdgcn_mfma_f32_16x16x32_bf16(af[i], bf[j], acc[i][j], 0, 0, 0);
  }

  const int col = lane & 15;
  const int rb = (lane >> 4) * 4;
#pragma unroll
  for (int j = 0; j < 4; ++j) {
    const int gn = n0 + wn + j * 16 + col;
    const float bv = bias[gn];
#pragma unroll
    for (int i = 0; i < 4; ++i)
#pragma unroll
      for (int r = 0; r < 4; ++r) {
        const int gm = m0 + wm + i * 16 + rb + r;
        outp[(size_t)gm * DIMC + gn] = f2bf(acc[i][j][r] + bv);
      }
  }
}

// ---------------- wo GEMM: 512 thr / 8 waves, double-buffered -----------------
__global__ __launch_bounds__(512)
void gemm_wo(const unsigned short* __restrict__ A,
             const unsigned short* __restrict__ Bw,
             const float* __restrict__ bias,
             float* __restrict__ outp)
{
  __shared__ __align__(16) unsigned short lA[2 * GBUF];
  __shared__ __align__(16) unsigned short lB[2 * GBUF];

  const int tid = threadIdx.x;
  const int wave = tid >> 6;          // 0..7
  const int lane = tid & 63;
  const int m0 = blockIdx.y * 128;
  const int n0 = blockIdx.x * 128;
  const int wm = (wave >> 1) * 32;    // 4 m-groups of 32
  const int wn = (wave & 1) * 64;     // 2 n-groups of 64

  f32x4 acc[2][4] = {};

  const int srow = tid >> 2;          // 0..127
  const int scol = (tid & 3) * 8;
  const int fr = lane & 15;
  const int fk = (lane >> 4) * 8;

  unsigned short* laS = lA + srow * 32 + scol;
  unsigned short* lbS = lB + srow * 32 + scol;
  const unsigned short* ga = A  + (size_t)(m0 + srow) * DIMC + scol;
  const unsigned short* gb = Bw + (size_t)(n0 + srow) * DIMC + scol;

  dma16(ga, laS);
  dma16(gb, lbS);

  for (int t = 0; t < 48; ++t) {
    const int cur = (t & 1) * GBUF;
    __syncthreads();
    if (t < 47) {
      const int nxt = GBUF - cur;
      const int k0n = (t + 1) * 32;
      dma16(ga + k0n, laS + nxt);
      dma16(gb + k0n, lbS + nxt);
    }

    bf16x8 af[2], bf[4];
#pragma unroll
    for (int i = 0; i < 2; ++i)
      af[i] = *(const bf16x8*)&lA[cur + (wm + i * 16 + fr) * 32 + fk];
#pragma unroll
    for (int j = 0; j < 4; ++j)
      bf[j] = *(const bf16x8*)&lB[cur + (wn + j * 16 + fr) * 32 + fk];
#pragma unroll
    for (int i = 0; i < 2; ++i)
#pragma unroll
      for (int j = 0; j < 4; ++j)
        acc[i][j] = __builtin_amdgcn_mfma_f32_16x16x32_bf16(af[i], bf[j], acc[i][j], 0, 0, 0);
  }

  const int col = lane & 15;
  const int rb = (lane >> 4) * 4;
#pragma unroll
  for (int j = 0; j < 4; ++j) {
    const int gn = n0 + wn + j * 16 + col;
    const float bv = bias[gn];
#pragma unroll
    for (int i = 0; i < 2; ++i)
#pragma unroll
      for (int r = 0; r < 4; ++r) {
        const int gm = m0 + wm + i * 16 + rb + r;
        outp[(size_t)gm * DIMC + gn] = acc[i][j][r] + bv;
      }
  }
}

// key permutation inside each 64-key tile (4-token groups stay contiguous):
// group G bits (g3 g2 g1 g0) -> G' = g3*8 + g1*4 + g0*2 + g2, chosen so the
// PV B-operand fragment IS the softmax output registers (P never in LDS).
__device__ __forceinline__ int vperm4(int G) {
  return (((G >> 3) & 1) << 3) | (((G >> 1) & 1) << 2) | ((G & 1) << 1) | ((G >> 2) & 1);
}

// ---------------- fused: rmsnorm+RoPE on q/k  AND  V transpose ----------------
__global__ __launch_bounds__(256)
void post_qkv_k(unsigned short* __restrict__ q, unsigned short* __restrict__ k,
                const unsigned short* __restrict__ v, unsigned short* __restrict__ vt,
                const float* __restrict__ nqw, const float* __restrict__ nkw,
                const float* __restrict__ freqs)
{
  const int bx = blockIdx.x;
  const int tid = threadIdx.x;
  if (bx < 2 * LTOK) {
    const int which = bx >= LTOK;
    const int tok = bx - which * LTOK;
    unsigned short* row = (which ? k : q) + (size_t)tok * DIMC;
    const float* nw = which ? nkw : nqw;
    const float sc = which ? 1.f : (0.08838834764831845f * 1.4426950408889634f);
    const int base = tid * 6;

    float vv[6];
    float ss = 0.f;
#pragma unroll
    for (int j = 0; j < 6; ++j) {
      vv[j] = bf2f(row[base + j]);
      ss += vv[j] * vv[j];
    }
#pragma unroll
    for (int off = 1; off < 64; off <<= 1) ss += __shfl_xor(ss, off);
    __shared__ float wsum[4];
    if ((tid & 63) == 0) wsum[tid >> 6] = ss;
    __syncthreads();
    const float total = wsum[0] + wsum[1] + wsum[2] + wsum[3];
    const float rms = rsqrtf(total * (1.f / DIMC) + 1e-6f);

    const int f = tok / FS;
    const int rem = tok - f * FS;
    const int h = rem / 24;
    const int w = rem - h * 24;

#pragma unroll
    for (int pp = 0; pp < 3; ++pp) {
      const int P = (base >> 1) + pp;
      const int p = P & 63;
      const int t = (p < 22) ? f : ((p < 43) ? h : w);
      const float fre = freqs[t * 128 + p * 2];
      const float fim = freqs[t * 128 + p * 2 + 1];
      const float e = vv[2 * pp]     * rms * nw[base + 2 * pp];
      const float o = vv[2 * pp + 1] * rms * nw[base + 2 * pp + 1];
      row[base + 2 * pp]     = f2bf((e * fre - o * fim) * sc);
      row[base + 2 * pp + 1] = f2bf((e * fim + o * fre) * sc);
    }
  } else {
    // V transpose with per-64-block key permutation: vt[d][64b+pi(i)] = v[64b+i][d]
    const int c0 = bx - 2 * LTOK;          // 0..1151
    const int tb = (c0 % 48) * 64;
    const int db = (c0 / 48) * 64;
    __shared__ __align__(16) unsigned short t[64 * 72];  // [dim][tok]
#pragma unroll
    for (int it = 0; it < 2; ++it) {
      int c = tid + it * 256;
      int tok = c >> 3, dc = (c & 7) * 8;
      uint4 val = *(const uint4*)(v + (size_t)(tb + tok) * DIMC + db + dc);
      unsigned short tmp[8];
      *(uint4*)tmp = val;
#pragma unroll
      for (int j = 0; j < 8; ++j) t[(dc + j) * 72 + tok] = tmp[j];
    }
    __syncthreads();
#pragma unroll
    for (int it = 0; it < 4; ++it) {
      int c = tid + it * 256;              // 0..1023
      int d = c >> 4, G = c & 15;          // 4-token group
      *(uint2*)(vt + ((size_t)db + d) * LTOK + tb + vperm4(G) * 4) =
          *(const uint2*)&t[d * 72 + G * 4];
    }
  }
}

// ---------------- MFMA flash attention v4 -------------------------------------
// v3 (R7) + double-buffered K/V LDS with prefetch-after-barrier: one barrier
// per tile, DMA of tile t+1 overlaps compute of tile t. LDS 64 KB -> 2
// blocks/CU (grid-limited at ~1.8 anyway). All R2-R7 SROA lessons kept:
// named scalars, bit_cast packing, no dynamic-indexed local arrays.
#define KBUF (64 * 128)
#define VBUF (128 * 64)
__global__ __launch_bounds__(256, 2)
void attn_flash(const unsigned short* __restrict__ q,
                const unsigned short* __restrict__ k,
                const unsigned short* __restrict__ vt,
                unsigned short* __restrict__ ab,
                float* __restrict__ Opart,
                float* __restrict__ mlbuf)
{
  const int bid = blockIdx.x;
  int qb, head, chunk, nchunks;
  if (bid < 360) { const int hb = bid >> 1; qb = 23 - hb / 12; head = hb % 12; chunk = bid & 1; nchunks = 2; }
  else           { const int lb = bid - 360; qb = 8 - lb / 12; head = lb % 12; chunk = 0; nchunks = 1; }

  const int q0 = qb * 128;              // 128 divides 384 -> block in one frame
  const int qf = qb / 3;
  const int kend = (qf + 1) * FS;
  const int s2 = kend - MAXATTN;
  const bool two = (s2 > FS);
  const int nt1 = (two ? FS : kend) >> 6;
  const int nt  = nt1 + (two ? (MAXATTN >> 6) : 0);
  const int half = nt / nchunks;        // even split for all 2-chunk rows
  const int tstart = chunk * half, tend = tstart + half;

  const int tid = threadIdx.x;
  const int wave = tid >> 6, lane = tid & 63;
  const int col = lane & 15;
  const int g = lane >> 4;
  const int g4 = g * 4;

  __shared__ __align__(16) unsigned short Kl[2 * KBUF];   // [key][dim], XOR-swizzled chunks
  __shared__ __align__(16) unsigned short Vtl[2 * VBUF];  // [d][key-perm], XOR-swizzled

  // Q fragments (B operand) for this wave's two 16-q subtiles
  bf16x8 qfA[4], qfB[4];
  {
    const unsigned short* qr0 = q + (size_t)(q0 + wave * 32 + col) * DIMC + head * HD;
#pragma unroll
    for (int kk = 0; kk < 4; ++kk) {
      qfA[kk] = *(const bf16x8*)(qr0 + kk * 32 + g * 8);
      qfB[kk] = *(const bf16x8*)(qr0 + (size_t)16 * DIMC + kk * 32 + g * 8);
    }
  }

  f32x4 o0[8] = {}, o1[8] = {};
  float m0 = -3.0e38f, l0 = 0.f, m1 = -3.0e38f, l1 = 0.f;

  // staging: thread tid <-> LDS chunk tid*16B; global source XOR-swizzled
  const int krow = tid >> 4;                         // 0..15 (K row within pass)
  const int kc8  = ((tid & 15) ^ krow) * 8;
  const unsigned short* kg = k + (size_t)krow * DIMC + head * HD + kc8;
  const int vrow = tid >> 3;                         // 0..31 (V row within pass)
  const int vc8  = ((tid & 7) ^ (vrow & 7)) * 8;
  const unsigned short* vg = vt + ((size_t)head * HD + vrow) * LTOK + vc8;
  unsigned short* kl = Kl + tid * 8;
  unsigned short* vl = Vtl + tid * 8;

  // prime buffer 0 with tile tstart
  {
    const int kb = (tstart < nt1) ? tstart * 64 : s2 + (tstart - nt1) * 64;
    const unsigned short* kp = kg + (size_t)kb * DIMC;
    dma16(kp,                     kl);
    dma16(kp + (size_t)16 * DIMC, kl + 16 * 128);
    dma16(kp + (size_t)32 * DIMC, kl + 32 * 128);
    dma16(kp + (size_t)48 * DIMC, kl + 48 * 128);
    const unsigned short* vp = vg + kb;
    dma16(vp,                     vl);
    dma16(vp + (size_t)32 * LTOK, vl + 32 * 64);
    dma16(vp + (size_t)64 * LTOK, vl + 64 * 64);
    dma16(vp + (size_t)96 * LTOK, vl + 96 * 64);
  }

  for (int t = tstart; t < tend; ++t) {
    const int kcur = ((t - tstart) & 1) * KBUF;
    const int vcur = ((t - tstart) & 1) * VBUF;
    __syncthreads();   // drains dma(t); joins all reads of previous buffer

    if (t + 1 < tend) {   // prefetch t+1 into other buffer; overlaps compute
      const int kb = (t + 1 < nt1) ? (t + 1) * 64 : s2 + (t + 1 - nt1) * 64;
      const int knxt = KBUF - kcur, vnxt = VBUF - vcur;
      const unsigned short* kp = kg + (size_t)kb * DIMC;
      dma16(kp,                     kl + knxt);
      dma16(kp + (size_t)16 * DIMC, kl + knxt + 16 * 128);
      dma16(kp + (size_t)32 * DIMC, kl + knxt + 32 * 128);
      dma16(kp + (size_t)48 * DIMC, kl + knxt + 48 * 128);
      const unsigned short* vp = vg + kb;
      dma16(vp,                     vl + vnxt);
      dma16(vp + (size_t)32 * LTOK, vl + vnxt + 32 * 64);
      dma16(vp + (size_t)64 * LTOK, vl + vnxt + 64 * 64);
      dma16(vp + (size_t)96 * LTOK, vl + vnxt + 96 * 64);
    }

    // S^T = K Q^T for both subtiles, sharing every K-fragment read
    f32x4 sA[4] = {}, sB[4] = {};
#pragma unroll
    for (int kt = 0; kt < 4; ++kt) {
      const unsigned short* kr = &Kl[kcur + (kt * 16 + col) * 128];
#pragma unroll
      for (int kk = 0; kk < 4; ++kk) {
        bf16x8 kfr = *(const bf16x8*)(kr + ((kk * 4 + g) ^ col) * 8);
        sA[kt] = __builtin_amdgcn_mfma_f32_16x16x32_bf16(kfr, qfA[kk], sA[kt], 0, 0, 0);
        sB[kt] = __builtin_amdgcn_mfma_f32_16x16x32_bf16(kfr, qfB[kk], sB[kt], 0, 0, 0);
      }
    }

    // ---- softmax subtile A (per-lane q=col; named P scalars) ----
    unsigned int A0, A1, A2, A3, A4, A5, A6, A7;
    float alA;
    {
      float mx = sA[0][0];
#pragma unroll
      for (int kt = 0; kt < 4; ++kt)
#pragma unroll
        for (int r = 0; r < 4; ++r) mx = fmaxf(mx, sA[kt][r]);
      mx = fmaxf(mx, __shfl_xor(mx, 16));
      mx = fmaxf(mx, __shfl_xor(mx, 32));
      const float mn = fmaxf(m0, mx);
      alA = exp2f(m0 - mn);
      m0 = mn;
      float rs = 0.f;
#define PKA(KT, PA, PB)                                        \
      {                                                        \
        const unsigned short p0 = f2bf(exp2f(sA[KT][0] - mn)); \
        const unsigned short p1 = f2bf(exp2f(sA[KT][1] - mn)); \
        const unsigned short p2 = f2bf(exp2f(sA[KT][2] - mn)); \
        const unsigned short p3 = f2bf(exp2f(sA[KT][3] - mn)); \
        rs += bf2f(p0) + bf2f(p1) + bf2f(p2) + bf2f(p3);       \
        PA = (unsigned int)p0 | ((unsigned int)p1 << 16);      \
        PB = (unsigned int)p2 | ((unsigned int)p3 << 16);      \
      }
      PKA(0, A0, A1) PKA(1, A2, A3) PKA(2, A4, A5) PKA(3, A6, A7)
#undef PKA
      rs += __shfl_xor(rs, 16);
      rs += __shfl_xor(rs, 32);
      l0 = l0 * alA + rs;
    }
    // ---- softmax subtile B ----
    unsigned int B0, B1, B2, B3, B4, B5, B6, B7;
    float alB;
    {
      float mx = sB[0][0];
#pragma unroll
      for (int kt = 0; kt < 4; ++kt)
#pragma unroll
        for (int r = 0; r < 4; ++r) mx = fmaxf(mx, sB[kt][r]);
      mx = fmaxf(mx, __shfl_xor(mx, 16));
      mx = fmaxf(mx, __shfl_xor(mx, 32));
      const float mn = fmaxf(m1, mx);
      alB = exp2f(m1 - mn);
      m1 = mn;
      float rs = 0.f;
#define PKB(KT, PA, PB)                                        \
      {                                                        \
        const unsigned short p0 = f2bf(exp2f(sB[KT][0] - mn)); \
        const unsigned short p1 = f2bf(exp2f(sB[KT][1] - mn)); \
        const unsigned short p2 = f2bf(exp2f(sB[KT][2] - mn)); \
        const unsigned short p3 = f2bf(exp2f(sB[KT][3] - mn)); \
        rs += bf2f(p0) + bf2f(p1) + bf2f(p2) + bf2f(p3);       \
        PA = (unsigned int)p0 | ((unsigned int)p1 << 16);      \
        PB = (unsigned int)p2 | ((unsigned int)p3 << 16);      \
      }
      PKB(0, B0, B1) PKB(1, B2, B3) PKB(2, B4, B5) PKB(3, B6, B7)
#undef PKB
      rs += __shfl_xor(rs, 16);
      rs += __shfl_xor(rs, 32);
      l1 = l1 * alB + rs;
    }

#pragma unroll
    for (int dt = 0; dt < 8; ++dt) { o0[dt] *= alA; o1[dt] *= alB; }

    // P fragments from named scalars via bit_cast (register-only)
    u32x4 tA0, tA1, tB0, tB1;
    tA0[0] = A0; tA0[1] = A1; tA0[2] = A2; tA0[3] = A3;
    tA1[0] = A4; tA1[1] = A5; tA1[2] = A6; tA1[3] = A7;
    tB0[0] = B0; tB0[1] = B1; tB0[2] = B2; tB0[3] = B3;
    tB1[0] = B4; tB1[1] = B5; tB1[2] = B6; tB1[3] = B7;
    const bf16x8 pfA0 = __builtin_bit_cast(bf16x8, tA0);
    const bf16x8 pfA1 = __builtin_bit_cast(bf16x8, tA1);
    const bf16x8 pfB0 = __builtin_bit_cast(bf16x8, tB0);
    const bf16x8 pfB1 = __builtin_bit_cast(bf16x8, tB1);

    // O^T += V^T P^T, sharing every V-fragment read between subtiles
    const int vx0 = (g ^ (col & 7)) * 8;         // step-0 chunk (swizzled)
    const int vx1 = ((4 + g) ^ (col & 7)) * 8;   // step-1 chunk
#pragma unroll
    for (int dt = 0; dt < 8; ++dt) {
      const unsigned short* vr = &Vtl[vcur + (dt * 16 + col) * 64];
      bf16x8 vf0 = *(const bf16x8*)(vr + vx0);
      o0[dt] = __builtin_amdgcn_mfma_f32_16x16x32_bf16(vf0, pfA0, o0[dt], 0, 0, 0);
      o1[dt] = __builtin_amdgcn_mfma_f32_16x16x32_bf16(vf0, pfB0, o1[dt], 0, 0, 0);
      bf16x8 vf1 = *(const bf16x8*)(vr + vx1);
      o0[dt] = __builtin_amdgcn_mfma_f32_16x16x32_bf16(vf1, pfA1, o0[dt], 0, 0, 0);
      o1[dt] = __builtin_amdgcn_mfma_f32_16x16x32_bf16(vf1, pfB1, o1[dt], 0, 0, 0);
    }
  }

  const int qrow0 = q0 + wave * 32 + col;       // subtile-A query token
  if (nchunks == 1) {
    const float i0 = 1.f / l0, i1 = 1.f / l1;
    unsigned short* or0 = ab + (size_t)qrow0 * DIMC + head * HD;
    unsigned short* or1 = or0 + (size_t)16 * DIMC;
#pragma unroll
    for (int dt = 0; dt < 8; ++dt) {
      uint2 pk;
      pk.x = (unsigned int)f2bf(o0[dt][0] * i0) | ((unsigned int)f2bf(o0[dt][1] * i0) << 16);
      pk.y = (unsigned int)f2bf(o0[dt][2] * i0) | ((unsigned int)f2bf(o0[dt][3] * i0) << 16);
      *(uint2*)(or0 + dt * 16 + g4) = pk;
      pk.x = (unsigned int)f2bf(o1[dt][0] * i1) | ((unsigned int)f2bf(o1[dt][1] * i1) << 16);
      pk.y = (unsigned int)f2bf(o1[dt][2] * i1) | ((unsigned int)f2bf(o1[dt][3] * i1) << 16);
      *(uint2*)(or1 + dt * 16 + g4) = pk;
    }
  } else {
    const int tokp0 = qrow0 - HTOK;
    float* ob0 = Opart + ((size_t)(chunk * NHT + tokp0) * HEADS + head) * HD;
    float* ob1 = Opart + ((size_t)(chunk * NHT + tokp0 + 16) * HEADS + head) * HD;
#pragma unroll
    for (int dt = 0; dt < 8; ++dt) {
      *(f32x4*)(ob0 + dt * 16 + g4) = o0[dt];
      *(f32x4*)(ob1 + dt * 16 + g4) = o1[dt];
    }
    if (lane < 16) {
      float* mlp0 = mlbuf + 2 * ((size_t)(chunk * NHT + tokp0) * HEADS + head);
      float* mlp1 = mlbuf + 2 * ((size_t)(chunk * NHT + tokp0 + 16) * HEADS + head);
      mlp0[0] = m0; mlp0[1] = l0;
      mlp1[0] = m1; mlp1[1] = l1;
    }
  }
}

// ---------------- merge the two K-chunks for heavy rows ----------------
__global__ __launch_bounds__(384)
void merge_k(const float* __restrict__ Opart, const float* __restrict__ mlbuf,
             unsigned short* __restrict__ ab)
{
  const int tokp = blockIdx.x;           // 0..1919
  const int tid = threadIdx.x;           // 0..383
  const int e = tid * 4;                 // elem in [0,1536)
  const int head = e >> 7;
  const size_t r0 = (size_t)tokp * DIMC + e;
  float4 o0 = *(const float4*)(Opart + r0);
  float4 o1 = *(const float4*)(Opart + (size_t)NHT * DIMC + r0);
  const float* ml0 = mlbuf + 2 * ((size_t)tokp * HEADS + head);
  const float* ml1 = mlbuf + 2 * ((size_t)(NHT + tokp) * HEADS + head);
  const float m0 = ml0[0], l0 = ml0[1], m1 = ml1[0], l1 = ml1[1];
  const float mm = fmaxf(m0, m1);
  const float a0 = exp2f(m0 - mm), a1 = exp2f(m1 - mm);
  const float inv = 1.f / (l0 * a0 + l1 * a1);
  uint2 pk;
  pk.x = (unsigned int)f2bf((o0.x * a0 + o1.x * a1) * inv) |
         ((unsigned int)f2bf((o0.y * a0 + o1.y * a1) * inv) << 16);
  pk.y = (unsigned int)f2bf((o0.z * a0 + o1.z * a1) * inv) |
         ((unsigned int)f2bf((o0.w * a0 + o1.w * a1) * inv) << 16);
  *(uint2*)(ab + (size_t)(HTOK + tokp) * DIMC + e) = pk;
}

// ---------------- launch ----------------
extern "C" void kernel_launch(void* const* d_in, const int* in_sizes, int n_in,
                              void* d_out, int out_size, void* d_ws, size_t ws_size,
                              hipStream_t stream)
{
  (void)in_sizes; (void)n_in; (void)out_size; (void)ws_size;
  const float* x     = (const float*)d_in[0];
  const float* freqs = (const float*)d_in[3];
  const float* wq    = (const float*)d_in[4];
  const float* bq    = (const float*)d_in[5];
  const float* wk    = (const float*)d_in[6];
  const float* bk    = (const float*)d_in[7];
  const float* wv    = (const float*)d_in[8];
  const float* bv    = (const float*)d_in[9];
  const float* wo    = (const float*)d_in[10];
  const float* bo    = (const float*)d_in[11];
  const float* nqw   = (const float*)d_in[12];
  const float* nkw   = (const float*)d_in[13];

  char* ws = (char*)d_ws;
  size_t off = 0;
  auto take = [&](size_t bytes) -> void* {
    void* p = ws + off; off += (bytes + 255) & ~(size_t)255; return p;
  };
  // wob first (must survive attention); xb..wvb are dead after QKV GEMM and
  // are overlaid by Opart (23,592,960 B, exact match).
  unsigned short* wob = (unsigned short*)take((size_t)DIMC * DIMC * 2);
  unsigned short* qb  = (unsigned short*)take((size_t)LTOK * DIMC * 2);
  unsigned short* kb  = (unsigned short*)take((size_t)LTOK * DIMC * 2);
  unsigned short* vb  = (unsigned short*)take((size_t)LTOK * DIMC * 2);
  unsigned short* ab  = (unsigned short*)take((size_t)LTOK * DIMC * 2);
  unsigned short* vtb = (unsigned short*)take((size_t)LTOK * DIMC * 2);
  unsigned short* xb  = (unsigned short*)take((size_t)LTOK * DIMC * 2);
  unsigned short* wqb = (unsigned short*)take((size_t)DIMC * DIMC * 2);
  unsigned short* wkb = (unsigned short*)take((size_t)DIMC * DIMC * 2);
  unsigned short* wvb = (unsigned short*)take((size_t)DIMC * DIMC * 2);
  float* mlb = (float*)take((size_t)2 * NHT * HEADS * 2 * sizeof(float));
  float* Opart = (float*)xb;   // overlays xb+wqb+wkb+wvb

  cvt_all_k<<<dim3(13824), dim3(256), 0, stream>>>(x, wq, wk, wv, wo,
                                                   xb, wqb, wkb, wvb, wob);

  gemm_qkv<<<dim3(DIMC / 128, LTOK / 128, 3), dim3(256), 0, stream>>>(
      xb, wqb, wkb, wvb, bq, bk, bv, qb, kb, vb);

  post_qkv_k<<<dim3(2 * LTOK + 1152), dim3(256), 0, stream>>>(
      qb, kb, vb, vtb, nqw, nkw, freqs);

  attn_flash<<<dim3(468), dim3(256), 0, stream>>>(qb, kb, vtb, ab, Opart, mlb);
  merge_k<<<dim3(NHT), dim3(384), 0, stream>>>(Opart, mlb, ab);

  gemm_wo<<<dim3(DIMC / 128, LTOK / 128), dim3(512), 0, stream>>>(
      ab, wob, bo, (float*)d_out);
}

// Round 9
// 284.989 us; speedup vs baseline: 1.1990x; 1.1175x over previous
//
#include <hip/hip_runtime.h>
#include <stdint.h>

#define DIMC 1536
#define LTOK 3072
#define HEADS 12
#define HD 128
#define FS 384            // H*W = 16*24
#define MAXATTN 1920
#define HTOK 1152         // first token with qf>=3 (2-chunk rows)
#define NHT 1920          // number of heavy tokens

typedef __attribute__((ext_vector_type(4))) float f32x4;
typedef __attribute__((ext_vector_type(8))) short bf16x8;
typedef __attribute__((ext_vector_type(4))) unsigned int u32x4;

__device__ __forceinline__ unsigned short f2bf(float f) {
  union { float f; unsigned int u; } c; c.f = f;
  unsigned int u = c.u + 0x7fffu + ((c.u >> 16) & 1u);   // RNE
  return (unsigned short)(u >> 16);
}
__device__ __forceinline__ float bf2f(unsigned short s) {
  union { unsigned int u; float f; } c; c.u = (unsigned int)s << 16; return c.f;
}

// async global->LDS DMA, 16B per lane; LDS dest must be wave-uniform base +
// lane*16 (all our staging offsets are tid*16B -> satisfied).
__device__ __forceinline__ void dma16(const void* g, void* l) {
  __builtin_amdgcn_global_load_lds(
      (const __attribute__((address_space(1))) unsigned int*)g,
      (__attribute__((address_space(3))) unsigned int*)l, 16, 0, 0);
}

// key permutation inside each 64-key tile (4-token groups stay contiguous):
// group G bits (g3 g2 g1 g0) -> G' = g3*8 + g1*4 + g0*2 + g2, chosen so the
// attention PV B-operand fragment IS the softmax output registers.
__device__ __forceinline__ int vperm4(int G) {
  return (((G >> 3) & 1) << 3) | (((G >> 1) & 1) << 2) | ((G & 1) << 1) | ((G >> 2) & 1);
}

// ---------------- fused fp32 -> bf16 conversion for all 5 tensors ----------------
__global__ __launch_bounds__(256)
void cvt_all_k(const float* __restrict__ x, const float* __restrict__ wq,
               const float* __restrict__ wk, const float* __restrict__ wv,
               const float* __restrict__ wo,
               unsigned short* __restrict__ xb, unsigned short* __restrict__ wqb,
               unsigned short* __restrict__ wkb, unsigned short* __restrict__ wvb,
               unsigned short* __restrict__ wob)
{
  const int i = blockIdx.x * 256 + threadIdx.x;      // uint4 index
  const int n0 = LTOK * DIMC / 4;
  const int nw = DIMC * DIMC / 4;
  const float* src; unsigned short* dst; int off;
  if (i < n0) { src = x; dst = xb; off = i; }
  else {
    int j = i - n0; int w = j / nw; off = j - w * nw;
    src = (w == 0) ? wq : (w == 1) ? wk : (w == 2) ? wv : wo;
    dst = (w == 0) ? wqb : (w == 1) ? wkb : (w == 2) ? wvb : wob;
  }
  float4 f = ((const float4*)src)[off];
  uint2 o;
  o.x = (unsigned int)f2bf(f.x) | ((unsigned int)f2bf(f.y) << 16);
  o.y = (unsigned int)f2bf(f.z) | ((unsigned int)f2bf(f.w) << 16);
  ((uint2*)dst)[off] = o;
}

// ---------------- QKV GEMM: 128x128 tile, BK=64, 256 thr, single-buffer -------
// XOR chunk swizzle baked into the GLOBAL source column during staging
// (LDS[row][s] = G[row][s ^ (row&7)]); read side applies the same XOR ->
// banks spread across all 8 groups (2-way aliasing = free).
// z==2 epilogue writes V transposed + vperm4-permuted directly into vt.
__global__ __launch_bounds__(256)
void gemm_qkv(const unsigned short* __restrict__ A,
              const unsigned short* __restrict__ B0,
              const unsigned short* __restrict__ B1,
              const unsigned short* __restrict__ B2,
              const float* __restrict__ bias0,
              const float* __restrict__ bias1,
              const float* __restrict__ bias2,
              unsigned short* __restrict__ o0, unsigned short* __restrict__ o1,
              unsigned short* __restrict__ vt)
{
  const int z = blockIdx.z;
  const unsigned short* Bw = (z == 0) ? B0 : (z == 1) ? B1 : B2;
  const float* bias = (z == 0) ? bias0 : (z == 1) ? bias1 : bias2;

  __shared__ __align__(16) unsigned short lA[128 * 64];
  __shared__ __align__(16) unsigned short lB[128 * 64];

  const int tid = threadIdx.x;
  const int wave = tid >> 6;
  const int lane = tid & 63;
  const int m0 = blockIdx.y * 128;
  const int n0 = blockIdx.x * 128;
  const int wm = (wave >> 1) * 64;
  const int wn = (wave & 1) * 64;

  f32x4 acc[4][4] = {};

  // staging: pass p covers rows [p*32, p*32+32); thread -> row=tid>>3,
  // stored chunk s=tid&7, global source chunk = s ^ (row&7).
  const int srow = tid >> 3;                    // 0..31
  const int scol = ((tid & 7) ^ (srow & 7)) * 8;
  const unsigned short* ga = A  + (size_t)(m0 + srow) * DIMC + scol;
  const unsigned short* gb = Bw + (size_t)(n0 + srow) * DIMC + scol;
  unsigned short* la = lA + tid * 8;
  unsigned short* lb = lB + tid * 8;

  const int fr = lane & 15;
  const int g = lane >> 4;
  const int fx = fr & 7;                        // read-side XOR term

  for (int k0 = 0; k0 < DIMC; k0 += 64) {
    dma16(ga + k0,                     la);
    dma16(ga + k0 + (size_t)32 * DIMC, la + 2048);
    dma16(ga + k0 + (size_t)64 * DIMC, la + 4096);
    dma16(ga + k0 + (size_t)96 * DIMC, la + 6144);
    dma16(gb + k0,                     lb);
    dma16(gb + k0 + (size_t)32 * DIMC, lb + 2048);
    dma16(gb + k0 + (size_t)64 * DIMC, lb + 4096);
    dma16(gb + k0 + (size_t)96 * DIMC, lb + 6144);
    __syncthreads();

#pragma unroll
    for (int kk = 0; kk < 2; ++kk) {
      const int cx = ((kk * 4 + g) ^ fx) * 8;   // swizzled chunk offset
      bf16x8 af[4], bf[4];
#pragma unroll
      for (int i = 0; i < 4; ++i)
        af[i] = *(const bf16x8*)&lA[(wm + i * 16 + fr) * 64 + cx];
#pragma unroll
      for (int j = 0; j < 4; ++j)
        bf[j] = *(const bf16x8*)&lB[(wn + j * 16 + fr) * 64 + cx];
#pragma unroll
      for (int i = 0; i < 4; ++i)
#pragma unroll
        for (int j = 0; j < 4; ++j)
          acc[i][j] = __builtin_amdgcn_mfma_f32_16x16x32_bf16(af[i], bf[j], acc[i][j], 0, 0, 0);
    }
    __syncthreads();
  }

  const int col = lane & 15;
  const int rb = (lane >> 4) * 4;
  if (z < 2) {
    unsigned short* outp = z ? o1 : o0;
#pragma unroll
    for (int j = 0; j < 4; ++j) {
      const int gn = n0 + wn + j * 16 + col;
      const float bv = bias[gn];
#pragma unroll
      for (int i = 0; i < 4; ++i)
#pragma unroll
        for (int r = 0; r < 4; ++r) {
          const int gm = m0 + wm + i * 16 + rb + r;
          outp[(size_t)gm * DIMC + gn] = f2bf(acc[i][j][r] + bv);
        }
    }
  } else {
    // vt[d][tok'] = v[tok][d] + bias, tok' = 64-tile base + vperm4(group)*4 + r
#pragma unroll
    for (int j = 0; j < 4; ++j) {
      const int gn = n0 + wn + j * 16 + col;      // d
      const float bv = bias[gn];
#pragma unroll
      for (int i = 0; i < 4; ++i) {
        const int base = wm + i * 16 + rb;        // within-128, multiple of 4
        const int tile = base & ~63;
        const int toka = m0 + tile + vperm4((base & 63) >> 2) * 4;
        uint2 pk;
        pk.x = (unsigned int)f2bf(acc[i][j][0] + bv) |
               ((unsigned int)f2bf(acc[i][j][1] + bv) << 16);
        pk.y = (unsigned int)f2bf(acc[i][j][2] + bv) |
               ((unsigned int)f2bf(acc[i][j][3] + bv) << 16);
        *(uint2*)(vt + (size_t)gn * LTOK + toka) = pk;
      }
    }
  }
}

// ---------------- wo GEMM: 64x128 tile (576 blocks), BK=64, single-buffer -----
__global__ __launch_bounds__(256)
void gemm_wo(const unsigned short* __restrict__ A,
             const unsigned short* __restrict__ Bw,
             const float* __restrict__ bias,
             float* __restrict__ outp)
{
  __shared__ __align__(16) unsigned short lA[64 * 64];
  __shared__ __align__(16) unsigned short lB[128 * 64];

  const int tid = threadIdx.x;
  const int wave = tid >> 6;
  const int lane = tid & 63;
  const int m0 = blockIdx.y * 64;
  const int n0 = blockIdx.x * 128;
  const int wm = (wave >> 1) * 32;
  const int wn = (wave & 1) * 64;

  f32x4 acc[2][4] = {};

  const int srow = tid >> 3;                    // 0..31
  const int scol = ((tid & 7) ^ (srow & 7)) * 8;
  const unsigned short* ga = A  + (size_t)(m0 + srow) * DIMC + scol;
  const unsigned short* gb = Bw + (size_t)(n0 + srow) * DIMC + scol;
  unsigned short* la = lA + tid * 8;
  unsigned short* lb = lB + tid * 8;

  const int fr = lane & 15;
  const int g = lane >> 4;
  const int fx = fr & 7;

  for (int k0 = 0; k0 < DIMC; k0 += 64) {
    dma16(ga + k0,                     la);
    dma16(ga + k0 + (size_t)32 * DIMC, la + 2048);
    dma16(gb + k0,                     lb);
    dma16(gb + k0 + (size_t)32 * DIMC, lb + 2048);
    dma16(gb + k0 + (size_t)64 * DIMC, lb + 4096);
    dma16(gb + k0 + (size_t)96 * DIMC, lb + 6144);
    __syncthreads();

#pragma unroll
    for (int kk = 0; kk < 2; ++kk) {
      const int cx = ((kk * 4 + g) ^ fx) * 8;
      bf16x8 af[2], bf[4];
#pragma unroll
      for (int i = 0; i < 2; ++i)
        af[i] = *(const bf16x8*)&lA[(wm + i * 16 + fr) * 64 + cx];
#pragma unroll
      for (int j = 0; j < 4; ++j)
        bf[j] = *(const bf16x8*)&lB[(wn + j * 16 + fr) * 64 + cx];
#pragma unroll
      for (int i = 0; i < 2; ++i)
#pragma unroll
        for (int j = 0; j < 4; ++j)
          acc[i][j] = __builtin_amdgcn_mfma_f32_16x16x32_bf16(af[i], bf[j], acc[i][j], 0, 0, 0);
    }
    __syncthreads();
  }

  const int col = lane & 15;
  const int rb = (lane >> 4) * 4;
#pragma unroll
  for (int j = 0; j < 4; ++j) {
    const int gn = n0 + wn + j * 16 + col;
    const float bv = bias[gn];
#pragma unroll
    for (int i = 0; i < 2; ++i)
#pragma unroll
      for (int r = 0; r < 4; ++r) {
        const int gm = m0 + wm + i * 16 + rb + r;
        outp[(size_t)gm * DIMC + gn] = acc[i][j][r] + bv;
      }
  }
}

// ---------------- rmsnorm + 3D RoPE on q/k (V transpose now in gemm_qkv) ------
__global__ __launch_bounds__(256)
void post_qkv_k(unsigned short* __restrict__ q, unsigned short* __restrict__ k,
                const float* __restrict__ nqw, const float* __restrict__ nkw,
                const float* __restrict__ freqs)
{
  const int bx = blockIdx.x;
  const int tid = threadIdx.x;
  const int which = bx >= LTOK;
  const int tok = bx - which * LTOK;
  unsigned short* row = (which ? k : q) + (size_t)tok * DIMC;
  const float* nw = which ? nkw : nqw;
  const float sc = which ? 1.f : (0.08838834764831845f * 1.4426950408889634f);
  const int base = tid * 6;

  float vv[6];
  float ss = 0.f;
#pragma unroll
  for (int j = 0; j < 6; ++j) {
    vv[j] = bf2f(row[base + j]);
    ss += vv[j] * vv[j];
  }
#pragma unroll
  for (int off = 1; off < 64; off <<= 1) ss += __shfl_xor(ss, off);
  __shared__ float wsum[4];
  if ((tid & 63) == 0) wsum[tid >> 6] = ss;
  __syncthreads();
  const float total = wsum[0] + wsum[1] + wsum[2] + wsum[3];
  const float rms = rsqrtf(total * (1.f / DIMC) + 1e-6f);

  const int f = tok / FS;
  const int rem = tok - f * FS;
  const int h = rem / 24;
  const int w = rem - h * 24;

#pragma unroll
  for (int pp = 0; pp < 3; ++pp) {
    const int P = (base >> 1) + pp;
    const int p = P & 63;
    const int t = (p < 22) ? f : ((p < 43) ? h : w);
    const float fre = freqs[t * 128 + p * 2];
    const float fim = freqs[t * 128 + p * 2 + 1];
    const float e = vv[2 * pp]     * rms * nw[base + 2 * pp];
    const float o = vv[2 * pp + 1] * rms * nw[base + 2 * pp + 1];
    row[base + 2 * pp]     = f2bf((e * fre - o * fim) * sc);
    row[base + 2 * pp + 1] = f2bf((e * fim + o * fre) * sc);
  }
}

// ---------------- MFMA flash attention v4 (R8, unchanged) ---------------------
#define KBUF (64 * 128)
#define VBUF (128 * 64)
__global__ __launch_bounds__(256, 2)
void attn_flash(const unsigned short* __restrict__ q,
                const unsigned short* __restrict__ k,
                const unsigned short* __restrict__ vt,
                unsigned short* __restrict__ ab,
                float* __restrict__ Opart,
                float* __restrict__ mlbuf)
{
  const int bid = blockIdx.x;
  int qb, head, chunk, nchunks;
  if (bid < 360) { const int hb = bid >> 1; qb = 23 - hb / 12; head = hb % 12; chunk = bid & 1; nchunks = 2; }
  else           { const int lb = bid - 360; qb = 8 - lb / 12; head = lb % 12; chunk = 0; nchunks = 1; }

  const int q0 = qb * 128;
  const int qf = qb / 3;
  const int kend = (qf + 1) * FS;
  const int s2 = kend - MAXATTN;
  const bool two = (s2 > FS);
  const int nt1 = (two ? FS : kend) >> 6;
  const int nt  = nt1 + (two ? (MAXATTN >> 6) : 0);
  const int half = nt / nchunks;
  const int tstart = chunk * half, tend = tstart + half;

  const int tid = threadIdx.x;
  const int wave = tid >> 6, lane = tid & 63;
  const int col = lane & 15;
  const int g = lane >> 4;
  const int g4 = g * 4;

  __shared__ __align__(16) unsigned short Kl[2 * KBUF];
  __shared__ __align__(16) unsigned short Vtl[2 * VBUF];

  bf16x8 qfA[4], qfB[4];
  {
    const unsigned short* qr0 = q + (size_t)(q0 + wave * 32 + col) * DIMC + head * HD;
#pragma unroll
    for (int kk = 0; kk < 4; ++kk) {
      qfA[kk] = *(const bf16x8*)(qr0 + kk * 32 + g * 8);
      qfB[kk] = *(const bf16x8*)(qr0 + (size_t)16 * DIMC + kk * 32 + g * 8);
    }
  }

  f32x4 o0[8] = {}, o1[8] = {};
  float m0 = -3.0e38f, l0 = 0.f, m1 = -3.0e38f, l1 = 0.f;

  const int krow = tid >> 4;
  const int kc8  = ((tid & 15) ^ krow) * 8;
  const unsigned short* kg = k + (size_t)krow * DIMC + head * HD + kc8;
  const int vrow = tid >> 3;
  const int vc8  = ((tid & 7) ^ (vrow & 7)) * 8;
  const unsigned short* vg = vt + ((size_t)head * HD + vrow) * LTOK + vc8;
  unsigned short* kl = Kl + tid * 8;
  unsigned short* vl = Vtl + tid * 8;

  {
    const int kb = (tstart < nt1) ? tstart * 64 : s2 + (tstart - nt1) * 64;
    const unsigned short* kp = kg + (size_t)kb * DIMC;
    dma16(kp,                     kl);
    dma16(kp + (size_t)16 * DIMC, kl + 16 * 128);
    dma16(kp + (size_t)32 * DIMC, kl + 32 * 128);
    dma16(kp + (size_t)48 * DIMC, kl + 48 * 128);
    const unsigned short* vp = vg + kb;
    dma16(vp,                     vl);
    dma16(vp + (size_t)32 * LTOK, vl + 32 * 64);
    dma16(vp + (size_t)64 * LTOK, vl + 64 * 64);
    dma16(vp + (size_t)96 * LTOK, vl + 96 * 64);
  }

  for (int t = tstart; t < tend; ++t) {
    const int kcur = ((t - tstart) & 1) * KBUF;
    const int vcur = ((t - tstart) & 1) * VBUF;
    __syncthreads();

    if (t + 1 < tend) {
      const int kb = (t + 1 < nt1) ? (t + 1) * 64 : s2 + (t + 1 - nt1) * 64;
      const int knxt = KBUF - kcur, vnxt = VBUF - vcur;
      const unsigned short* kp = kg + (size_t)kb * DIMC;
      dma16(kp,                     kl + knxt);
      dma16(kp + (size_t)16 * DIMC, kl + knxt + 16 * 128);
      dma16(kp + (size_t)32 * DIMC, kl + knxt + 32 * 128);
      dma16(kp + (size_t)48 * DIMC, kl + knxt + 48 * 128);
      const unsigned short* vp = vg + kb;
      dma16(vp,                     vl + vnxt);
      dma16(vp + (size_t)32 * LTOK, vl + vnxt + 32 * 64);
      dma16(vp + (size_t)64 * LTOK, vl + vnxt + 64 * 64);
      dma16(vp + (size_t)96 * LTOK, vl + vnxt + 96 * 64);
    }

    f32x4 sA[4] = {}, sB[4] = {};
#pragma unroll
    for (int kt = 0; kt < 4; ++kt) {
      const unsigned short* kr = &Kl[kcur + (kt * 16 + col) * 128];
#pragma unroll
      for (int kk = 0; kk < 4; ++kk) {
        bf16x8 kfr = *(const bf16x8*)(kr + ((kk * 4 + g) ^ col) * 8);
        sA[kt] = __builtin_amdgcn_mfma_f32_16x16x32_bf16(kfr, qfA[kk], sA[kt], 0, 0, 0);
        sB[kt] = __builtin_amdgcn_mfma_f32_16x16x32_bf16(kfr, qfB[kk], sB[kt], 0, 0, 0);
      }
    }

    unsigned int A0, A1, A2, A3, A4, A5, A6, A7;
    float alA;
    {
      float mx = sA[0][0];
#pragma unroll
      for (int kt = 0; kt < 4; ++kt)
#pragma unroll
        for (int r = 0; r < 4; ++r) mx = fmaxf(mx, sA[kt][r]);
      mx = fmaxf(mx, __shfl_xor(mx, 16));
      mx = fmaxf(mx, __shfl_xor(mx, 32));
      const float mn = fmaxf(m0, mx);
      alA = exp2f(m0 - mn);
      m0 = mn;
      float rs = 0.f;
#define PKA(KT, PA, PB)                                        \
      {                                                        \
        const unsigned short p0 = f2bf(exp2f(sA[KT][0] - mn)); \
        const unsigned short p1 = f2bf(exp2f(sA[KT][1] - mn)); \
        const unsigned short p2 = f2bf(exp2f(sA[KT][2] - mn)); \
        const unsigned short p3 = f2bf(exp2f(sA[KT][3] - mn)); \
        rs += bf2f(p0) + bf2f(p1) + bf2f(p2) + bf2f(p3);       \
        PA = (unsigned int)p0 | ((unsigned int)p1 << 16);      \
        PB = (unsigned int)p2 | ((unsigned int)p3 << 16);      \
      }
      PKA(0, A0, A1) PKA(1, A2, A3) PKA(2, A4, A5) PKA(3, A6, A7)
#undef PKA
      rs += __shfl_xor(rs, 16);
      rs += __shfl_xor(rs, 32);
      l0 = l0 * alA + rs;
    }
    unsigned int B0, B1, B2, B3, B4, B5, B6, B7;
    float alB;
    {
      float mx = sB[0][0];
#pragma unroll
      for (int kt = 0; kt < 4; ++kt)
#pragma unroll
        for (int r = 0; r < 4; ++r) mx = fmaxf(mx, sB[kt][r]);
      mx = fmaxf(mx, __shfl_xor(mx, 16));
      mx = fmaxf(mx, __shfl_xor(mx, 32));
      const float mn = fmaxf(m1, mx);
      alB = exp2f(m1 - mn);
      m1 = mn;
      float rs = 0.f;
#define PKB(KT, PA, PB)                                        \
      {                                                        \
        const unsigned short p0 = f2bf(exp2f(sB[KT][0] - mn)); \
        const unsigned short p1 = f2bf(exp2f(sB[KT][1] - mn)); \
        const unsigned short p2 = f2bf(exp2f(sB[KT][2] - mn)); \
        const unsigned short p3 = f2bf(exp2f(sB[KT][3] - mn)); \
        rs += bf2f(p0) + bf2f(p1) + bf2f(p2) + bf2f(p3);       \
        PA = (unsigned int)p0 | ((unsigned int)p1 << 16);      \
        PB = (unsigned int)p2 | ((unsigned int)p3 << 16);      \
      }
      PKB(0, B0, B1) PKB(1, B2, B3) PKB(2, B4, B5) PKB(3, B6, B7)
#undef PKB
      rs += __shfl_xor(rs, 16);
      rs += __shfl_xor(rs, 32);
      l1 = l1 * alB + rs;
    }

#pragma unroll
    for (int dt = 0; dt < 8; ++dt) { o0[dt] *= alA; o1[dt] *= alB; }

    u32x4 tA0, tA1, tB0, tB1;
    tA0[0] = A0; tA0[1] = A1; tA0[2] = A2; tA0[3] = A3;
    tA1[0] = A4; tA1[1] = A5; tA1[2] = A6; tA1[3] = A7;
    tB0[0] = B0; tB0[1] = B1; tB0[2] = B2; tB0[3] = B3;
    tB1[0] = B4; tB1[1] = B5; tB1[2] = B6; tB1[3] = B7;
    const bf16x8 pfA0 = __builtin_bit_cast(bf16x8, tA0);
    const bf16x8 pfA1 = __builtin_bit_cast(bf16x8, tA1);
    const bf16x8 pfB0 = __builtin_bit_cast(bf16x8, tB0);
    const bf16x8 pfB1 = __builtin_bit_cast(bf16x8, tB1);

    const int vx0 = (g ^ (col & 7)) * 8;
    const int vx1 = ((4 + g) ^ (col & 7)) * 8;
#pragma unroll
    for (int dt = 0; dt < 8; ++dt) {
      const unsigned short* vr = &Vtl[vcur + (dt * 16 + col) * 64];
      bf16x8 vf0 = *(const bf16x8*)(vr + vx0);
      o0[dt] = __builtin_amdgcn_mfma_f32_16x16x32_bf16(vf0, pfA0, o0[dt], 0, 0, 0);
      o1[dt] = __builtin_amdgcn_mfma_f32_16x16x32_bf16(vf0, pfB0, o1[dt], 0, 0, 0);
      bf16x8 vf1 = *(const bf16x8*)(vr + vx1);
      o0[dt] = __builtin_amdgcn_mfma_f32_16x16x32_bf16(vf1, pfA1, o0[dt], 0, 0, 0);
      o1[dt] = __builtin_amdgcn_mfma_f32_16x16x32_bf16(vf1, pfB1, o1[dt], 0, 0, 0);
    }
  }

  const int qrow0 = q0 + wave * 32 + col;
  if (nchunks == 1) {
    const float i0 = 1.f / l0, i1 = 1.f / l1;
    unsigned short* or0 = ab + (size_t)qrow0 * DIMC + head * HD;
    unsigned short* or1 = or0 + (size_t)16 * DIMC;
#pragma unroll
    for (int dt = 0; dt < 8; ++dt) {
      uint2 pk;
      pk.x = (unsigned int)f2bf(o0[dt][0] * i0) | ((unsigned int)f2bf(o0[dt][1] * i0) << 16);
      pk.y = (unsigned int)f2bf(o0[dt][2] * i0) | ((unsigned int)f2bf(o0[dt][3] * i0) << 16);
      *(uint2*)(or0 + dt * 16 + g4) = pk;
      pk.x = (unsigned int)f2bf(o1[dt][0] * i1) | ((unsigned int)f2bf(o1[dt][1] * i1) << 16);
      pk.y = (unsigned int)f2bf(o1[dt][2] * i1) | ((unsigned int)f2bf(o1[dt][3] * i1) << 16);
      *(uint2*)(or1 + dt * 16 + g4) = pk;
    }
  } else {
    const int tokp0 = qrow0 - HTOK;
    float* ob0 = Opart + ((size_t)(chunk * NHT + tokp0) * HEADS + head) * HD;
    float* ob1 = Opart + ((size_t)(chunk * NHT + tokp0 + 16) * HEADS + head) * HD;
#pragma unroll
    for (int dt = 0; dt < 8; ++dt) {
      *(f32x4*)(ob0 + dt * 16 + g4) = o0[dt];
      *(f32x4*)(ob1 + dt * 16 + g4) = o1[dt];
    }
    if (lane < 16) {
      float* mlp0 = mlbuf + 2 * ((size_t)(chunk * NHT + tokp0) * HEADS + head);
      float* mlp1 = mlbuf + 2 * ((size_t)(chunk * NHT + tokp0 + 16) * HEADS + head);
      mlp0[0] = m0; mlp0[1] = l0;
      mlp1[0] = m1; mlp1[1] = l1;
    }
  }
}

// ---------------- merge the two K-chunks for heavy rows ----------------
__global__ __launch_bounds__(384)
void merge_k(const float* __restrict__ Opart, const float* __restrict__ mlbuf,
             unsigned short* __restrict__ ab)
{
  const int tokp = blockIdx.x;
  const int tid = threadIdx.x;
  const int e = tid * 4;
  const int head = e >> 7;
  const size_t r0 = (size_t)tokp * DIMC + e;
  float4 o0 = *(const float4*)(Opart + r0);
  float4 o1 = *(const float4*)(Opart + (size_t)NHT * DIMC + r0);
  const float* ml0 = mlbuf + 2 * ((size_t)tokp * HEADS + head);
  const float* ml1 = mlbuf + 2 * ((size_t)(NHT + tokp) * HEADS + head);
  const float m0 = ml0[0], l0 = ml0[1], m1 = ml1[0], l1 = ml1[1];
  const float mm = fmaxf(m0, m1);
  const float a0 = exp2f(m0 - mm), a1 = exp2f(m1 - mm);
  const float inv = 1.f / (l0 * a0 + l1 * a1);
  uint2 pk;
  pk.x = (unsigned int)f2bf((o0.x * a0 + o1.x * a1) * inv) |
         ((unsigned int)f2bf((o0.y * a0 + o1.y * a1) * inv) << 16);
  pk.y = (unsigned int)f2bf((o0.z * a0 + o1.z * a1) * inv) |
         ((unsigned int)f2bf((o0.w * a0 + o1.w * a1) * inv) << 16);
  *(uint2*)(ab + (size_t)(HTOK + tokp) * DIMC + e) = pk;
}

// ---------------- launch ----------------
extern "C" void kernel_launch(void* const* d_in, const int* in_sizes, int n_in,
                              void* d_out, int out_size, void* d_ws, size_t ws_size,
                              hipStream_t stream)
{
  (void)in_sizes; (void)n_in; (void)out_size; (void)ws_size;
  const float* x     = (const float*)d_in[0];
  const float* freqs = (const float*)d_in[3];
  const float* wq    = (const float*)d_in[4];
  const float* bq    = (const float*)d_in[5];
  const float* wk    = (const float*)d_in[6];
  const float* bk    = (const float*)d_in[7];
  const float* wv    = (const float*)d_in[8];
  const float* bv    = (const float*)d_in[9];
  const float* wo    = (const float*)d_in[10];
  const float* bo    = (const float*)d_in[11];
  const float* nqw   = (const float*)d_in[12];
  const float* nkw   = (const float*)d_in[13];

  char* ws = (char*)d_ws;
  size_t off = 0;
  auto take = [&](size_t bytes) -> void* {
    void* p = ws + off; off += (bytes + 255) & ~(size_t)255; return p;
  };
  unsigned short* wob = (unsigned short*)take((size_t)DIMC * DIMC * 2);
  unsigned short* qb  = (unsigned short*)take((size_t)LTOK * DIMC * 2);
  unsigned short* kb  = (unsigned short*)take((size_t)LTOK * DIMC * 2);
  unsigned short* vb  = (unsigned short*)take((size_t)LTOK * DIMC * 2);  // unused (layout kept)
  unsigned short* ab  = (unsigned short*)take((size_t)LTOK * DIMC * 2);
  unsigned short* vtb = (unsigned short*)take((size_t)LTOK * DIMC * 2);
  unsigned short* xb  = (unsigned short*)take((size_t)LTOK * DIMC * 2);
  unsigned short* wqb = (unsigned short*)take((size_t)DIMC * DIMC * 2);
  unsigned short* wkb = (unsigned short*)take((size_t)DIMC * DIMC * 2);
  unsigned short* wvb = (unsigned short*)take((size_t)DIMC * DIMC * 2);
  float* mlb = (float*)take((size_t)2 * NHT * HEADS * 2 * sizeof(float));
  float* Opart = (float*)xb;   // overlays xb+wqb+wkb+wvb (dead after QKV GEMM)
  (void)vb;

  cvt_all_k<<<dim3(13824), dim3(256), 0, stream>>>(x, wq, wk, wv, wo,
                                                   xb, wqb, wkb, wvb, wob);

  gemm_qkv<<<dim3(DIMC / 128, LTOK / 128, 3), dim3(256), 0, stream>>>(
      xb, wqb, wkb, wvb, bq, bk, bv, qb, kb, vtb);

  post_qkv_k<<<dim3(2 * LTOK), dim3(256), 0, stream>>>(qb, kb, nqw, nkw, freqs);

  attn_flash<<<dim3(468), dim3(256), 0, stream>>>(qb, kb, vtb, ab, Opart, mlb);
  merge_k<<<dim3(NHT), dim3(384), 0, stream>>>(Opart, mlb, ab);

  gemm_wo<<<dim3(DIMC / 128, LTOK / 64), dim3(256), 0, stream>>>(
      ab, wob, bo, (float*)d_out);
}